// Round 3
// baseline (1413.939 us; speedup 1.0000x reference)
//
#include <hip/hip_runtime.h>

#define NODES 10000
#define EDGES 160000
#define INF_ 16
#define DD 512
#define GRAPHS 64
#define NOUT 18
#define BN_EPS 1e-5f

__global__ void k_zero_i32(int* p, int n) { int i = blockIdx.x * 256 + threadIdx.x; if (i < n) p[i] = 0; }
__global__ void k_zero_f32(float* p, int n) { int i = blockIdx.x * 256 + threadIdx.x; if (i < n) p[i] = 0.f; }

// ---- CSR build (dst-indexed): count -> scan -> fill ----
__global__ void k_count(const int* __restrict__ dst, int* __restrict__ cnt) {
  int e = blockIdx.x * 256 + threadIdx.x;
  if (e < EDGES) atomicAdd(&cnt[dst[e]], 1);
}

__global__ __launch_bounds__(1024) void k_scan(const int* __restrict__ cnt, int* __restrict__ rowptr) {
  __shared__ int s[1024];
  int t = threadIdx.x;
  int base = t * 10;
  int c[10]; int sum = 0;
#pragma unroll
  for (int i = 0; i < 10; ++i) { int idx = base + i; c[i] = (idx < NODES) ? cnt[idx] : 0; sum += c[i]; }
  s[t] = sum; __syncthreads();
  for (int off = 1; off < 1024; off <<= 1) {
    int v = s[t];
    int a = (t >= off) ? s[t - off] : 0;
    __syncthreads();
    s[t] = v + a;
    __syncthreads();
  }
  int run = (t == 0) ? 0 : s[t - 1];
#pragma unroll
  for (int i = 0; i < 10; ++i) { int idx = base + i; if (idx < NODES) rowptr[idx] = run; run += c[i]; }
  if (t == 1023) rowptr[NODES] = s[1023];
}

__global__ void k_fill(const int* __restrict__ src, const int* __restrict__ dst,
                       const int* __restrict__ rowptr, int* __restrict__ cur, int* __restrict__ col) {
  int e = blockIdx.x * 256 + threadIdx.x;
  if (e < EDGES) {
    int d = dst[e];
    int p = atomicAdd(&cur[d], 1);
    col[rowptr[d] + p] = src[e];
  }
}

// ---- layer-1 aggregation on [NODES,16] fp32 ----
__global__ void k_agg16(const float* __restrict__ x, const int* __restrict__ rowptr,
                        const int* __restrict__ col, float* __restrict__ h0) {
  int t = threadIdx.x;
  int node = blockIdx.x * 16 + (t >> 4);
  int c = t & 15;
  if (node >= NODES) return;
  float acc = x[node * INF_ + c];
  int r1 = rowptr[node + 1];
  for (int idx = rowptr[node]; idx < r1; ++idx) {
    int j = col[idx];
    acc += x[j * INF_ + c];
  }
  h0[node * INF_ + c] = acc;
}

// ---- z1 = relu(h0 @ W1a + b1a), K=16 ----
__global__ void k_gemm_k16(const float* __restrict__ h0, const float* __restrict__ W,
                           const float* __restrict__ bias, float* __restrict__ out) {
  int r = blockIdx.y;
  int c = blockIdx.x * 256 + threadIdx.x;
  float acc = bias[c];
#pragma unroll
  for (int k = 0; k < INF_; ++k)
    acc = fmaf(h0[r * INF_ + k], W[k * DD + c], acc);
  out[r * DD + c] = fmaxf(acc, 0.f);
}

// ---- fused aggregation + BN-apply on [NODES,512] ----
// out[n][c] = sc[c]*(h[n][c] + sum_j h[j][c]) + (1+deg)*sh[c]
__global__ __launch_bounds__(128) void k_agg512_bn(const float* __restrict__ h, const int* __restrict__ rowptr,
                                                   const int* __restrict__ col, const float* __restrict__ ss,
                                                   float* __restrict__ out) {
  int node = blockIdx.x;
  int c4 = threadIdx.x * 4;
  const float4* hv = (const float4*)h;
  float4 acc = hv[(node * DD + c4) >> 2];
  int r0 = rowptr[node], r1 = rowptr[node + 1];
  for (int idx = r0; idx < r1; ++idx) {
    int j = col[idx];
    float4 v = hv[(j * DD + c4) >> 2];
    acc.x += v.x; acc.y += v.y; acc.z += v.z; acc.w += v.w;
  }
  float n = (float)(r1 - r0 + 1);
  float4 sc = *(const float4*)(ss + c4);
  float4 sh = *(const float4*)(ss + DD + c4);
  acc.x = sc.x * acc.x + n * sh.x;
  acc.y = sc.y * acc.y + n * sh.y;
  acc.z = sc.z * acc.z + n * sh.z;
  acc.w = sc.w * acc.w + n * sh.w;
  ((float4*)out)[(node * DD + c4) >> 2] = acc;
}

// ---- fp32 SGEMM: C[M,512] = relu(A[M,512] @ W[512,512] + bias) ----
// 128x128 tile, 256 threads, 8x8 per thread (split col/row halves), BK=16.
// STATS=1: also accumulates per-column sum / sumsq of post-relu C into stats[0..511|512..1023].
template <int STATS>
__global__ __launch_bounds__(256, 2) void sgemm128(
    const float* __restrict__ A, const float* __restrict__ W,
    const float* __restrict__ bias, float* __restrict__ C, int M,
    float* __restrict__ stats) {
  __shared__ float smem[2 * 16 * 128];
  float* As = smem;              // [16][128] : As[k][row]
  float* Ws = smem + 16 * 128;   // [16][128] : Ws[k][col]
  const int t = threadIdx.x;
  const int bm = blockIdx.y * 128;
  const int bn = blockIdx.x * 128;
  const int tx = t & 15, ty = t >> 4;
  const int ar = t >> 1;          // 0..127 (A row in tile)
  const int ak = (t & 1) * 8;     // 0 or 8 (A k in tile)
  const int wk = t >> 4;          // 0..15
  const int wc = (t & 15) * 8;    // 0..120
  const int arow = bm + ar;
  float acc[8][8] = {};
  const float* Aptr = A + (size_t)arow * 512 + ak;
  const float* Wptr = W + (size_t)wk * 512 + bn + wc;

  for (int k0 = 0; k0 < 512; k0 += 16) {
    float4 a0 = make_float4(0.f, 0.f, 0.f, 0.f), a1 = a0;
    if (arow < M) {
      a0 = *(const float4*)(Aptr + k0);
      a1 = *(const float4*)(Aptr + k0 + 4);
    }
    float4 w0 = *(const float4*)(Wptr + (size_t)k0 * 512);
    float4 w1 = *(const float4*)(Wptr + (size_t)k0 * 512 + 4);
    As[(ak + 0) * 128 + ar] = a0.x; As[(ak + 1) * 128 + ar] = a0.y;
    As[(ak + 2) * 128 + ar] = a0.z; As[(ak + 3) * 128 + ar] = a0.w;
    As[(ak + 4) * 128 + ar] = a1.x; As[(ak + 5) * 128 + ar] = a1.y;
    As[(ak + 6) * 128 + ar] = a1.z; As[(ak + 7) * 128 + ar] = a1.w;
    *(float4*)&Ws[wk * 128 + wc] = w0;
    *(float4*)&Ws[wk * 128 + wc + 4] = w1;
    __syncthreads();
#pragma unroll
    for (int kk = 0; kk < 16; ++kk) {
      const float* ap = &As[kk * 128];
      const float* bp = &Ws[kk * 128];
      float4 a0v = *(const float4*)(ap + ty * 4);
      float4 a1v = *(const float4*)(ap + 64 + ty * 4);
      float4 b0v = *(const float4*)(bp + tx * 4);
      float4 b1v = *(const float4*)(bp + 64 + tx * 4);
      float av[8] = {a0v.x, a0v.y, a0v.z, a0v.w, a1v.x, a1v.y, a1v.z, a1v.w};
      float bv[8] = {b0v.x, b0v.y, b0v.z, b0v.w, b1v.x, b1v.y, b1v.z, b1v.w};
#pragma unroll
      for (int i = 0; i < 8; ++i)
#pragma unroll
        for (int j = 0; j < 8; ++j)
          acc[i][j] = fmaf(av[i], bv[j], acc[i][j]);
    }
    __syncthreads();
  }

  float bva[8];
#pragma unroll
  for (int j = 0; j < 8; ++j) {
    int cj = (j < 4) ? tx * 4 + j : 64 + tx * 4 + (j - 4);
    bva[j] = bias[bn + cj];
  }
  float colS[8] = {}, colQ[8] = {};
#pragma unroll
  for (int i = 0; i < 8; ++i) {
    int row = bm + ((i < 4) ? ty * 4 + i : 64 + ty * 4 + (i - 4));
    if (row < M) {
      float v[8];
#pragma unroll
      for (int j = 0; j < 8; ++j) {
        v[j] = fmaxf(acc[i][j] + bva[j], 0.f);
        if (STATS) { colS[j] += v[j]; colQ[j] += v[j] * v[j]; }
      }
      *(float4*)(C + (size_t)row * 512 + bn + tx * 4) = make_float4(v[0], v[1], v[2], v[3]);
      *(float4*)(C + (size_t)row * 512 + bn + 64 + tx * 4) = make_float4(v[4], v[5], v[6], v[7]);
    }
  }
  if (STATS) {
    __syncthreads();
#pragma unroll
    for (int j = 0; j < 8; ++j) {
      int cj = (j < 4) ? tx * 4 + j : 64 + tx * 4 + (j - 4);
      As[ty * 128 + cj] = colS[j];
      Ws[ty * 128 + cj] = colQ[j];
    }
    __syncthreads();
    if (t < 128) {
      float s = 0.f;
#pragma unroll
      for (int g = 0; g < 16; ++g) s += As[g * 128 + t];
      atomicAdd(&stats[bn + t], s);
    } else {
      int c = t - 128;
      float q = 0.f;
#pragma unroll
      for (int g = 0; g < 16; ++g) q += Ws[g * 128 + c];
      atomicAdd(&stats[512 + bn + c], q);
    }
  }
}

__global__ void k_bn_finalize(const float* __restrict__ sums, const float* __restrict__ gamma,
                              const float* __restrict__ beta, float* __restrict__ ss) {
  int c = threadIdx.x;  // block 512
  float mean = sums[c] * (1.f / NODES);
  float var = sums[DD + c] * (1.f / NODES) - mean * mean;
  float sc = gamma[c] * rsqrtf(var + BN_EPS);
  ss[c] = sc;
  ss[DD + c] = beta[c] - mean * sc;
}

// ---- pooling ----
__global__ void k_pool_cnt(const int* __restrict__ batch, float* __restrict__ gcnt) {
  int r = blockIdx.x * 256 + threadIdx.x;
  if (r < NODES) atomicAdd(&gcnt[batch[r]], 1.f);
}

__global__ __launch_bounds__(128) void k_pool_sum(const float* __restrict__ h, const int* __restrict__ batch,
                                                  float* __restrict__ gsum) {
  int c4 = threadIdx.x * 4;
  int r0 = blockIdx.x * 100;
  int r1 = min(r0 + 100, NODES);
  if (r0 >= r1) return;
  float4 acc = make_float4(0.f, 0.f, 0.f, 0.f);
  int gcur = batch[r0];
  for (int r = r0; r < r1; ++r) {
    int g = batch[r];
    if (g != gcur) {
      atomicAdd(&gsum[gcur * DD + c4 + 0], acc.x);
      atomicAdd(&gsum[gcur * DD + c4 + 1], acc.y);
      atomicAdd(&gsum[gcur * DD + c4 + 2], acc.z);
      atomicAdd(&gsum[gcur * DD + c4 + 3], acc.w);
      acc = make_float4(0.f, 0.f, 0.f, 0.f);
      gcur = g;
    }
    float4 v = *(const float4*)(h + r * DD + c4);
    acc.x += v.x; acc.y += v.y; acc.z += v.z; acc.w += v.w;
  }
  atomicAdd(&gsum[gcur * DD + c4 + 0], acc.x);
  atomicAdd(&gsum[gcur * DD + c4 + 1], acc.y);
  atomicAdd(&gsum[gcur * DD + c4 + 2], acc.z);
  atomicAdd(&gsum[gcur * DD + c4 + 3], acc.w);
}

// ---- head: feats = tanh(bn(pooled) @ Wfc + bfc), BN applied to mean ----
__global__ __launch_bounds__(512) void k_head(const float* __restrict__ gsum, const float* __restrict__ gcnt,
                                              const float* __restrict__ ss,
                                              const float* __restrict__ Wfc, const float* __restrict__ bfc,
                                              float* __restrict__ feats) {
  __shared__ float pv[512];
  int g = blockIdx.x, c = threadIdx.x;
  float inv = 1.f / fmaxf(gcnt[g], 1.f);
  pv[c] = gsum[g * DD + c] * inv * ss[c] + ss[DD + c];
  __syncthreads();
  float acc = bfc[c];
  for (int k = 0; k < DD; ++k)
    acc = fmaf(pv[k], Wfc[k * DD + c], acc);
  feats[g * DD + c] = tanhf(acc);
}

// ---- logits = feats @ Wlog + blog, out fp32 ----
__global__ void k_logits(const float* __restrict__ feats, const float* __restrict__ Wlog,
                         const float* __restrict__ blog, float* __restrict__ out) {
  int g = blockIdx.x, o = threadIdx.x;
  if (o >= NOUT) return;
  float acc = blog[o];
  const float* f = feats + g * DD;
  for (int k = 0; k < DD; ++k)
    acc = fmaf(f[k], Wlog[k * NOUT + o], acc);
  out[g * NOUT + o] = acc;
}

extern "C" void kernel_launch(void* const* d_in, const int* in_sizes, int n_in,
                              void* d_out, int out_size, void* d_ws, size_t ws_size,
                              hipStream_t stream) {
  const float* x = (const float*)d_in[0];
  const int* ei = (const int*)d_in[1];
  const int* batch = (const int*)d_in[2];
  const float* W1a = (const float*)d_in[3];
  const float* b1a = (const float*)d_in[4];
  const float* W1b = (const float*)d_in[5];
  const float* b1b = (const float*)d_in[6];
  const float* Wa = (const float*)d_in[7];
  const float* ba = (const float*)d_in[8];
  const float* Wb = (const float*)d_in[9];
  const float* bb = (const float*)d_in[10];
  const float* bng = (const float*)d_in[11];
  const float* bnb = (const float*)d_in[12];
  const float* Wfc = (const float*)d_in[13];
  const float* bfc = (const float*)d_in[14];
  const float* Wlog = (const float*)d_in[15];
  const float* blog = (const float*)d_in[16];
  float* out = (float*)d_out;

  const int* src = ei;
  const int* dstp = ei + EDGES;

  char* w = (char*)d_ws;
  int* rowptr  = (int*)(w);                 // 10001 i32
  int* cur     = (int*)(w + 40192);         // 10000 i32
  int* col     = (int*)(w + 80384);         // 160000 i32
  float* h0    = (float*)(w + 720384);      // 160000 f (reused as feats later)
  float* feats = (float*)(w + 720384);      // 32768 f (alias of h0; h0 dead by then)
  float* bns   = (float*)(w + 1360384);     // 5 x 1024 f (sum|sumsq per layer)
  float* bnss  = (float*)(w + 1380864);     // 5 x 1024 f (scale|shift per layer)
  float* gsum  = (float*)(w + 1401344);     // 32768 f
  float* gcnt  = (float*)(w + 1532416);     // 64 f (contiguous after gsum)
  float* bufA  = (float*)(w + 1532928);     // 5,120,000 f
  float* bufB  = (float*)(w + 22012928);    // 5,120,000 f (end ~42.49 MB)

  // CSR build
  k_zero_i32<<<40, 256, 0, stream>>>(cur, NODES);
  k_count<<<625, 256, 0, stream>>>(dstp, cur);
  k_scan<<<1, 1024, 0, stream>>>(cur, rowptr);
  k_zero_i32<<<40, 256, 0, stream>>>(cur, NODES);
  k_fill<<<625, 256, 0, stream>>>(src, dstp, rowptr, cur, col);

  // zero bns (5x1024) .. bnss (harmless) .. gsum .. gcnt in one pass: 43072 floats
  k_zero_f32<<<169, 256, 0, stream>>>(bns, 43072);

  // layer 1: agg16 -> relu(K16 matmul) -> relu(matmul W1b)+stats -> finalize
  k_agg16<<<625, 256, 0, stream>>>(x, rowptr, col, h0);
  k_gemm_k16<<<dim3(2, NODES), 256, 0, stream>>>(h0, W1a, b1a, bufA);
  sgemm128<1><<<dim3(4, 79), 256, 0, stream>>>(bufA, W1b, b1b, bufB, NODES, bns);
  k_bn_finalize<<<1, 512, 0, stream>>>(bns, bng, bnb, bnss);

  // layers 2..5 (ping-pong): agg+bn -> relu(matmul Wa) -> relu(matmul Wb)+stats -> finalize
  float* H = bufB;
  float* T = bufA;
  for (int i = 0; i < 4; ++i) {
    k_agg512_bn<<<NODES, 128, 0, stream>>>(H, rowptr, col, bnss + i * 1024, T);
    sgemm128<0><<<dim3(4, 79), 256, 0, stream>>>(T, Wa + i * DD * DD, ba + i * DD, H, NODES, nullptr);
    sgemm128<1><<<dim3(4, 79), 256, 0, stream>>>(H, Wb + i * DD * DD, bb + i * DD, T, NODES, bns + (i + 1) * 1024);
    k_bn_finalize<<<1, 512, 0, stream>>>(bns + (i + 1) * 1024, bng + (i + 1) * DD, bnb + (i + 1) * DD,
                                         bnss + (i + 1) * 1024);
    float* tmp = H; H = T; T = tmp;
  }

  // pooling (raw h; layer-5 BN folded into head) + head
  k_pool_cnt<<<40, 256, 0, stream>>>(batch, gcnt);
  k_pool_sum<<<100, 128, 0, stream>>>(H, batch, gsum);
  k_head<<<GRAPHS, 512, 0, stream>>>(gsum, gcnt, bnss + 4 * 1024, Wfc, bfc, feats);
  k_logits<<<GRAPHS, 64, 0, stream>>>(feats, Wlog, blog, out);
}

// Round 5
// 756.785 us; speedup vs baseline: 1.8683x; 1.8683x over previous
//
#include <hip/hip_runtime.h>

#define NODES 10000
#define EDGES 160000
#define INF_ 16
#define DD 512
#define GRAPHS 64
#define NOUT 18
#define BN_EPS 1e-5f
#define LOSCALE 1024.f

using u16 = unsigned short;
typedef __attribute__((ext_vector_type(8))) _Float16 f16x8;
typedef __attribute__((ext_vector_type(4))) float f32x4;

__device__ __forceinline__ float h2f(u16 u) {
  union { u16 u; _Float16 h; } v; v.u = u; return (float)v.h;
}
__device__ __forceinline__ u16 f2h(float f) {
  union { u16 u; _Float16 h; } v; v.h = (_Float16)f; return v.u;
}

__global__ void k_zero_i32(int* p, int n) { int i = blockIdx.x * 256 + threadIdx.x; if (i < n) p[i] = 0; }
__global__ void k_zero_f32(float* p, int n) { int i = blockIdx.x * 256 + threadIdx.x; if (i < n) p[i] = 0.f; }

// ---- CSR build (dst-indexed): count -> scan -> fill ----
__global__ void k_count(const int* __restrict__ dst, int* __restrict__ cnt) {
  int e = blockIdx.x * 256 + threadIdx.x;
  if (e < EDGES) atomicAdd(&cnt[dst[e]], 1);
}

__global__ __launch_bounds__(1024) void k_scan(const int* __restrict__ cnt, int* __restrict__ rowptr) {
  __shared__ int s[1024];
  int t = threadIdx.x;
  int base = t * 10;
  int c[10]; int sum = 0;
#pragma unroll
  for (int i = 0; i < 10; ++i) { int idx = base + i; c[i] = (idx < NODES) ? cnt[idx] : 0; sum += c[i]; }
  s[t] = sum; __syncthreads();
  for (int off = 1; off < 1024; off <<= 1) {
    int v = s[t];
    int a = (t >= off) ? s[t - off] : 0;
    __syncthreads();
    s[t] = v + a;
    __syncthreads();
  }
  int run = (t == 0) ? 0 : s[t - 1];
#pragma unroll
  for (int i = 0; i < 10; ++i) { int idx = base + i; if (idx < NODES) rowptr[idx] = run; run += c[i]; }
  if (t == 1023) rowptr[NODES] = s[1023];
}

__global__ void k_fill(const int* __restrict__ src, const int* __restrict__ dst,
                       const int* __restrict__ rowptr, int* __restrict__ cur, int* __restrict__ col) {
  int e = blockIdx.x * 256 + threadIdx.x;
  if (e < EDGES) {
    int d = dst[e];
    int p = atomicAdd(&cur[d], 1);
    col[rowptr[d] + p] = src[e];
  }
}

// ---- W transpose + split into fp16 hi + fp16 (lo*1024) planes: Wt[n][k] = W[k][n] ----
// z: 0 -> W1b, 1..4 -> Wa[i], 5..8 -> Wb[i].
__global__ __launch_bounds__(256) void k_wsplit(const float* __restrict__ W1b, const float* __restrict__ Wa,
                                                const float* __restrict__ Wb, u16* __restrict__ Wt) {
  __shared__ float tile[32][33];
  int z = blockIdx.z;
  const float* src = (z == 0) ? W1b : (z <= 4 ? Wa + (z - 1) * DD * DD : Wb + (z - 5) * DD * DD);
  int kb = blockIdx.y * 32, nb = blockIdx.x * 32;
  int tx = threadIdx.x & 31, ty = threadIdx.x >> 5;  // 32 x 8
#pragma unroll
  for (int i = 0; i < 4; ++i)
    tile[ty + 8 * i][tx] = src[(kb + ty + 8 * i) * DD + nb + tx];
  __syncthreads();
  u16* hi = Wt + (size_t)z * 524288;
  u16* lo = hi + 262144;
#pragma unroll
  for (int i = 0; i < 4; ++i) {
    int n = nb + ty + 8 * i, k = kb + tx;
    float v = tile[tx][ty + 8 * i];
    u16 h = f2h(v);
    hi[n * DD + k] = h;
    lo[n * DD + k] = f2h((v - h2f(h)) * LOSCALE);
  }
}

// ---- layer-1 aggregation on [NODES,16] fp32 ----
__global__ void k_agg16(const float* __restrict__ x, const int* __restrict__ rowptr,
                        const int* __restrict__ col, float* __restrict__ h0) {
  int t = threadIdx.x;
  int node = blockIdx.x * 16 + (t >> 4);
  int c = t & 15;
  if (node >= NODES) return;
  float acc = x[node * INF_ + c];
  int r1 = rowptr[node + 1];
  for (int idx = rowptr[node]; idx < r1; ++idx) {
    int j = col[idx];
    acc += x[j * INF_ + c];
  }
  h0[node * INF_ + c] = acc;
}

// ---- z1 = relu(h0 @ W1a + b1a), K=16, fp16 out ----
__global__ void k_gemm_k16(const float* __restrict__ h0, const float* __restrict__ W,
                           const float* __restrict__ bias, u16* __restrict__ out) {
  int r = blockIdx.y;
  int c = blockIdx.x * 256 + threadIdx.x;
  float acc = bias[c];
#pragma unroll
  for (int k = 0; k < INF_; ++k)
    acc = fmaf(h0[r * INF_ + k], W[k * DD + c], acc);
  out[r * DD + c] = f2h(fmaxf(acc, 0.f));
}

// ---- fused aggregation + BN-apply on [NODES,512] fp16 in / fp16 out ----
// out[n][c] = sc[c]*(h[n][c] + sum_j h[j][c]) + (1+deg)*sh[c]
__global__ __launch_bounds__(128) void k_agg512_bn(const u16* __restrict__ h, const int* __restrict__ rowptr,
                                                   const int* __restrict__ col, const float* __restrict__ ss,
                                                   u16* __restrict__ out) {
  int node = blockIdx.x;
  int c4 = threadIdx.x * 4;
  ushort4 s = *(const ushort4*)(h + node * DD + c4);
  float4 acc = make_float4(h2f(s.x), h2f(s.y), h2f(s.z), h2f(s.w));
  int r0 = rowptr[node], r1 = rowptr[node + 1];
  for (int idx = r0; idx < r1; ++idx) {
    int j = col[idx];
    ushort4 v = *(const ushort4*)(h + j * DD + c4);
    acc.x += h2f(v.x); acc.y += h2f(v.y); acc.z += h2f(v.z); acc.w += h2f(v.w);
  }
  float n = (float)(r1 - r0 + 1);
  float4 sc = *(const float4*)(ss + c4);
  float4 sh = *(const float4*)(ss + DD + c4);
  ushort4 o;
  o.x = f2h(sc.x * acc.x + n * sh.x);
  o.y = f2h(sc.y * acc.y + n * sh.y);
  o.z = f2h(sc.z * acc.z + n * sh.z);
  o.w = f2h(sc.w * acc.w + n * sh.w);
  *(ushort4*)(out + node * DD + c4) = o;
}

// ---- MFMA GEMM: C[M,512] = relu(A[M,512](fp16) @ (Wh + Wl/1024)[512,512] + bias), fp16 out ----
// Wt layout: [n][k] (pre-transposed), hi plane then scaled-lo plane (+262144).
// BM=64 BN=128 BK=64; 256 thr = 4 waves, wave computes 32x64 via 2x4 16x16x32 MFMAs (x2 acc sets).
// STATS=1: per-column sum/sumsq of post-relu C -> stats[0..511 | 512..1023].
template <int STATS>
__global__ __launch_bounds__(256, 2) void mfma_gemm(
    const u16* __restrict__ A, const u16* __restrict__ Wt,
    const float* __restrict__ bias, u16* __restrict__ C, int M,
    float* __restrict__ stats) {
  __shared__ u16 lds[23040];           // 46080 B
  u16* As = lds;                       // [64][72]
  u16* Wh = lds + 4608;                // [128][72]
  u16* Wl = lds + 13824;               // [128][72]
  const int T = threadIdx.x;
  const int bm = blockIdx.y * 64;
  const int bn = blockIdx.x * 128;
  const int lane = T & 63;
  const int wave = T >> 6;
  const int wm = (wave & 1) * 32;
  const int wn = (wave >> 1) * 64;
  const int q = lane >> 4;
  const int r16 = lane & 15;

  f32x4 accH[2][4] = {};
  f32x4 accL[2][4] = {};

  for (int k0 = 0; k0 < 512; k0 += 64) {
    // stage A tile (guarded rows -> zeros)
#pragma unroll
    for (int p = 0; p < 2; ++p) {
      int c = T + 256 * p;
      int row = c >> 3, kc = c & 7;
      int grow = bm + row;
      uint4 z = make_uint4(0u, 0u, 0u, 0u);
      if (grow < M) z = *(const uint4*)(A + (size_t)grow * DD + k0 + kc * 8);
      *(uint4*)(As + row * 72 + kc * 8) = z;
    }
    // stage W tiles (hi + lo)
#pragma unroll
    for (int p = 0; p < 4; ++p) {
      int c = T + 256 * p;
      int row = c >> 3, kc = c & 7;
      const u16* srcp = Wt + (size_t)(bn + row) * DD + k0 + kc * 8;
      *(uint4*)(Wh + row * 72 + kc * 8) = *(const uint4*)(srcp);
      *(uint4*)(Wl + row * 72 + kc * 8) = *(const uint4*)(srcp + 262144);
    }
    __syncthreads();
#pragma unroll
    for (int ks = 0; ks < 2; ++ks) {
      int kb = ks * 32 + q * 8;
      f16x8 af[2], bh[4], bl[4];
#pragma unroll
      for (int mt = 0; mt < 2; ++mt)
        af[mt] = *(const f16x8*)(As + (wm + mt * 16 + r16) * 72 + kb);
#pragma unroll
      for (int nt = 0; nt < 4; ++nt) {
        bh[nt] = *(const f16x8*)(Wh + (wn + nt * 16 + r16) * 72 + kb);
        bl[nt] = *(const f16x8*)(Wl + (wn + nt * 16 + r16) * 72 + kb);
      }
#pragma unroll
      for (int mt = 0; mt < 2; ++mt)
#pragma unroll
        for (int nt = 0; nt < 4; ++nt) {
          accH[mt][nt] = __builtin_amdgcn_mfma_f32_16x16x32_f16(af[mt], bh[nt], accH[mt][nt], 0, 0, 0);
          accL[mt][nt] = __builtin_amdgcn_mfma_f32_16x16x32_f16(af[mt], bl[nt], accL[mt][nt], 0, 0, 0);
        }
    }
    __syncthreads();
  }

  // epilogue: combine hi/lo accumulators + bias + relu + fp16 store (+ optional BN stats)
  float colS[4] = {}, colQ[4] = {};
#pragma unroll
  for (int nt = 0; nt < 4; ++nt) {
    int n = bn + wn + nt * 16 + r16;
    float bv = bias[n];
#pragma unroll
    for (int mt = 0; mt < 2; ++mt) {
#pragma unroll
      for (int rr = 0; rr < 4; ++rr) {
        int row = bm + wm + mt * 16 + q * 4 + rr;
        if (row < M) {
          float v = fmaxf(accH[mt][nt][rr] + accL[mt][nt][rr] * (1.f / LOSCALE) + bv, 0.f);
          C[(size_t)row * DD + n] = f2h(v);
          if (STATS) { colS[nt] += v; colQ[nt] += v * v; }
        }
      }
    }
  }
  if (STATS) {
#pragma unroll
    for (int nt = 0; nt < 4; ++nt) {
      float s = colS[nt], qq = colQ[nt];
      s += __shfl_xor(s, 16); s += __shfl_xor(s, 32);
      qq += __shfl_xor(qq, 16); qq += __shfl_xor(qq, 32);
      if (q == 0) {
        int n = bn + wn + nt * 16 + r16;
        atomicAdd(&stats[n], s);
        atomicAdd(&stats[DD + n], qq);
      }
    }
  }
}

__global__ void k_bn_finalize(const float* __restrict__ sums, const float* __restrict__ gamma,
                              const float* __restrict__ beta, float* __restrict__ ss) {
  int c = threadIdx.x;  // block 512
  float mean = sums[c] * (1.f / NODES);
  float var = sums[DD + c] * (1.f / NODES) - mean * mean;
  float sc = gamma[c] * rsqrtf(var + BN_EPS);
  ss[c] = sc;
  ss[DD + c] = beta[c] - mean * sc;
}

// ---- pooling (fp16 h) ----
__global__ void k_pool_cnt(const int* __restrict__ batch, float* __restrict__ gcnt) {
  int r = blockIdx.x * 256 + threadIdx.x;
  if (r < NODES) atomicAdd(&gcnt[batch[r]], 1.f);
}

__global__ __launch_bounds__(128) void k_pool_sum(const u16* __restrict__ h, const int* __restrict__ batch,
                                                  float* __restrict__ gsum) {
  int c4 = threadIdx.x * 4;
  int r0 = blockIdx.x * 100;
  int r1 = min(r0 + 100, NODES);
  if (r0 >= r1) return;
  float4 acc = make_float4(0.f, 0.f, 0.f, 0.f);
  int gcur = batch[r0];
  for (int r = r0; r < r1; ++r) {
    int g = batch[r];
    if (g != gcur) {
      atomicAdd(&gsum[gcur * DD + c4 + 0], acc.x);
      atomicAdd(&gsum[gcur * DD + c4 + 1], acc.y);
      atomicAdd(&gsum[gcur * DD + c4 + 2], acc.z);
      atomicAdd(&gsum[gcur * DD + c4 + 3], acc.w);
      acc = make_float4(0.f, 0.f, 0.f, 0.f);
      gcur = g;
    }
    ushort4 v = *(const ushort4*)(h + r * DD + c4);
    acc.x += h2f(v.x); acc.y += h2f(v.y); acc.z += h2f(v.z); acc.w += h2f(v.w);
  }
  atomicAdd(&gsum[gcur * DD + c4 + 0], acc.x);
  atomicAdd(&gsum[gcur * DD + c4 + 1], acc.y);
  atomicAdd(&gsum[gcur * DD + c4 + 2], acc.z);
  atomicAdd(&gsum[gcur * DD + c4 + 3], acc.w);
}

// ---- head: feats = tanh(bn(pooled) @ Wfc + bfc), layer-5 BN folded in ----
__global__ __launch_bounds__(512) void k_head(const float* __restrict__ gsum, const float* __restrict__ gcnt,
                                              const float* __restrict__ ss,
                                              const float* __restrict__ Wfc, const float* __restrict__ bfc,
                                              float* __restrict__ feats) {
  __shared__ float pv[512];
  int g = blockIdx.x, c = threadIdx.x;
  float inv = 1.f / fmaxf(gcnt[g], 1.f);
  pv[c] = gsum[g * DD + c] * inv * ss[c] + ss[DD + c];
  __syncthreads();
  float acc = bfc[c];
  for (int k = 0; k < DD; ++k)
    acc = fmaf(pv[k], Wfc[k * DD + c], acc);
  feats[g * DD + c] = tanhf(acc);
}

// ---- logits = feats @ Wlog + blog, out fp32 ----
__global__ void k_logits(const float* __restrict__ feats, const float* __restrict__ Wlog,
                         const float* __restrict__ blog, float* __restrict__ out) {
  int g = blockIdx.x, o = threadIdx.x;
  if (o >= NOUT) return;
  float acc = blog[o];
  const float* f = feats + g * DD;
  for (int k = 0; k < DD; ++k)
    acc = fmaf(f[k], Wlog[k * NOUT + o], acc);
  out[g * NOUT + o] = acc;
}

extern "C" void kernel_launch(void* const* d_in, const int* in_sizes, int n_in,
                              void* d_out, int out_size, void* d_ws, size_t ws_size,
                              hipStream_t stream) {
  const float* x = (const float*)d_in[0];
  const int* ei = (const int*)d_in[1];
  const int* batch = (const int*)d_in[2];
  const float* W1a = (const float*)d_in[3];
  const float* b1a = (const float*)d_in[4];
  const float* W1b = (const float*)d_in[5];
  const float* b1b = (const float*)d_in[6];
  const float* Wa = (const float*)d_in[7];
  const float* ba = (const float*)d_in[8];
  const float* Wb = (const float*)d_in[9];
  const float* bb = (const float*)d_in[10];
  const float* bng = (const float*)d_in[11];
  const float* bnb = (const float*)d_in[12];
  const float* Wfc = (const float*)d_in[13];
  const float* bfc = (const float*)d_in[14];
  const float* Wlog = (const float*)d_in[15];
  const float* blog = (const float*)d_in[16];
  float* out = (float*)d_out;

  const int* src = ei;
  const int* dstp = ei + EDGES;

  char* w = (char*)d_ws;
  int* rowptr  = (int*)(w);                 // 10001 i32
  int* cur     = (int*)(w + 40192);         // 10000 i32
  int* col     = (int*)(w + 80384);         // 160000 i32
  float* h0    = (float*)(w + 720384);      // 160000 f
  float* bns   = (float*)(w + 1360384);     // 5 x 1024 f
  float* bnss  = (float*)(w + 1380864);     // 5 x 1024 f
  float* gsum  = (float*)(w + 1401344);     // 32768 f
  float* gcnt  = (float*)(w + 1532416);     // 64 f (contiguous after gsum)
  float* feats = (float*)(w + 1532672);     // 32768 f
  u16* Wt      = (u16*)(w + 1663744);       // 9 x (hi 262144 + lo 262144) u16 = 9.44 MB
  u16* P0      = (u16*)(w + 11100928);      // 5,120,000 fp16
  u16* P1      = (u16*)(w + 21340928);      // 5,120,000 fp16 (end ~31.6 MB)

  // CSR build
  k_zero_i32<<<40, 256, 0, stream>>>(cur, NODES);
  k_count<<<625, 256, 0, stream>>>(dstp, cur);
  k_scan<<<1, 1024, 0, stream>>>(cur, rowptr);
  k_zero_i32<<<40, 256, 0, stream>>>(cur, NODES);
  k_fill<<<625, 256, 0, stream>>>(src, dstp, rowptr, cur, col);

  // zero bns | bnss | gsum | gcnt (contiguous 43072 floats)
  k_zero_f32<<<169, 256, 0, stream>>>(bns, 43072);

  // weight transpose + hi/lo split (9 DxD matrices)
  k_wsplit<<<dim3(16, 16, 9), 256, 0, stream>>>(W1b, Wa, Wb, Wt);

  // layer 1
  k_agg16<<<625, 256, 0, stream>>>(x, rowptr, col, h0);
  k_gemm_k16<<<dim3(2, NODES), 256, 0, stream>>>(h0, W1a, b1a, P0);
  mfma_gemm<1><<<dim3(4, 157), 256, 0, stream>>>(P0, Wt, b1b, P1, NODES, bns);
  k_bn_finalize<<<1, 512, 0, stream>>>(bns, bng, bnb, bnss);

  // layers 2..5: H -> agg+bn -> T -> mfma(Wa) -> H -> mfma(Wb)+stats -> T
  u16* H = P1;
  u16* T = P0;
  for (int i = 0; i < 4; ++i) {
    k_agg512_bn<<<NODES, 128, 0, stream>>>(H, rowptr, col, bnss + i * 1024, T);
    mfma_gemm<0><<<dim3(4, 157), 256, 0, stream>>>(T, Wt + (size_t)(1 + i) * 524288, ba + i * DD, H, NODES, nullptr);
    mfma_gemm<1><<<dim3(4, 157), 256, 0, stream>>>(H, Wt + (size_t)(5 + i) * 524288, bb + i * DD, T, NODES,
                                                   bns + (i + 1) * 1024);
    k_bn_finalize<<<1, 512, 0, stream>>>(bns + (i + 1) * 1024, bng + (i + 1) * DD, bnb + (i + 1) * DD,
                                         bnss + (i + 1) * 1024);
    u16* tmp = H; H = T; T = tmp;
  }

  // pooling (raw fp16 h; layer-5 BN folded into head) + head
  k_pool_cnt<<<40, 256, 0, stream>>>(batch, gcnt);
  k_pool_sum<<<100, 128, 0, stream>>>(H, batch, gsum);
  k_head<<<GRAPHS, 512, 0, stream>>>(gsum, gcnt, bnss + 4 * 1024, Wfc, bfc, feats);
  k_logits<<<GRAPHS, 64, 0, stream>>>(feats, Wlog, blog, out);
}

// Round 6
// 711.089 us; speedup vs baseline: 1.9884x; 1.0643x over previous
//
#include <hip/hip_runtime.h>

#define NODES 10000
#define EDGES 160000
#define INF_ 16
#define DD 512
#define GRAPHS 64
#define NOUT 18
#define BN_EPS 1e-5f
#define LOSCALE 1024.f

using u16 = unsigned short;
typedef __attribute__((ext_vector_type(8))) _Float16 f16x8;
typedef __attribute__((ext_vector_type(4))) float f32x4;

__device__ __forceinline__ float h2f(u16 u) {
  union { u16 u; _Float16 h; } v; v.u = u; return (float)v.h;
}
__device__ __forceinline__ u16 f2h(float f) {
  union { u16 u; _Float16 h; } v; v.h = (_Float16)f; return v.u;
}
__device__ __forceinline__ void add8(uint4 u, float* a) {
  a[0] += h2f((u16)(u.x & 0xffff)); a[1] += h2f((u16)(u.x >> 16));
  a[2] += h2f((u16)(u.y & 0xffff)); a[3] += h2f((u16)(u.y >> 16));
  a[4] += h2f((u16)(u.z & 0xffff)); a[5] += h2f((u16)(u.z >> 16));
  a[6] += h2f((u16)(u.w & 0xffff)); a[7] += h2f((u16)(u.w >> 16));
}
__device__ __forceinline__ unsigned int pk(float a, float b) {
  return (unsigned int)f2h(a) | ((unsigned int)f2h(b) << 16);
}

__global__ void k_zero_i32(int* p, int n) { int i = blockIdx.x * 256 + threadIdx.x; if (i < n) p[i] = 0; }
__global__ void k_zero_f32(float* p, int n) { int i = blockIdx.x * 256 + threadIdx.x; if (i < n) p[i] = 0.f; }

// ---- CSR build (dst-indexed): count -> scan -> fill ----
__global__ void k_count(const int* __restrict__ dst, int* __restrict__ cnt) {
  int e = blockIdx.x * 256 + threadIdx.x;
  if (e < EDGES) atomicAdd(&cnt[dst[e]], 1);
}

__global__ __launch_bounds__(1024) void k_scan(const int* __restrict__ cnt, int* __restrict__ rowptr) {
  __shared__ int s[1024];
  int t = threadIdx.x;
  int base = t * 10;
  int c[10]; int sum = 0;
#pragma unroll
  for (int i = 0; i < 10; ++i) { int idx = base + i; c[i] = (idx < NODES) ? cnt[idx] : 0; sum += c[i]; }
  s[t] = sum; __syncthreads();
  for (int off = 1; off < 1024; off <<= 1) {
    int v = s[t];
    int a = (t >= off) ? s[t - off] : 0;
    __syncthreads();
    s[t] = v + a;
    __syncthreads();
  }
  int run = (t == 0) ? 0 : s[t - 1];
#pragma unroll
  for (int i = 0; i < 10; ++i) { int idx = base + i; if (idx < NODES) rowptr[idx] = run; run += c[i]; }
  if (t == 1023) rowptr[NODES] = s[1023];
}

__global__ void k_fill(const int* __restrict__ src, const int* __restrict__ dst,
                       const int* __restrict__ rowptr, int* __restrict__ cur, int* __restrict__ col) {
  int e = blockIdx.x * 256 + threadIdx.x;
  if (e < EDGES) {
    int d = dst[e];
    int p = atomicAdd(&cur[d], 1);
    col[rowptr[d] + p] = src[e];
  }
}

// ---- W transpose + split into fp16 hi + fp16 (lo*1024) planes: Wt[n][k] = W[k][n] ----
// z: 0 -> W1b, 1..4 -> Wa[i], 5..8 -> Wb[i].
__global__ __launch_bounds__(256) void k_wsplit(const float* __restrict__ W1b, const float* __restrict__ Wa,
                                                const float* __restrict__ Wb, u16* __restrict__ Wt) {
  __shared__ float tile[32][33];
  int z = blockIdx.z;
  const float* src = (z == 0) ? W1b : (z <= 4 ? Wa + (z - 1) * DD * DD : Wb + (z - 5) * DD * DD);
  int kb = blockIdx.y * 32, nb = blockIdx.x * 32;
  int tx = threadIdx.x & 31, ty = threadIdx.x >> 5;  // 32 x 8
#pragma unroll
  for (int i = 0; i < 4; ++i)
    tile[ty + 8 * i][tx] = src[(kb + ty + 8 * i) * DD + nb + tx];
  __syncthreads();
  u16* hi = Wt + (size_t)z * 524288;
  u16* lo = hi + 262144;
#pragma unroll
  for (int i = 0; i < 4; ++i) {
    int n = nb + ty + 8 * i, k = kb + tx;
    float v = tile[tx][ty + 8 * i];
    u16 h = f2h(v);
    hi[n * DD + k] = h;
    lo[n * DD + k] = f2h((v - h2f(h)) * LOSCALE);
  }
}

// ---- layer-1 aggregation on [NODES,16] fp32 ----
__global__ void k_agg16(const float* __restrict__ x, const int* __restrict__ rowptr,
                        const int* __restrict__ col, float* __restrict__ h0) {
  int t = threadIdx.x;
  int node = blockIdx.x * 16 + (t >> 4);
  int c = t & 15;
  if (node >= NODES) return;
  float acc = x[node * INF_ + c];
  int r1 = rowptr[node + 1];
  for (int idx = rowptr[node]; idx < r1; ++idx) {
    int j = col[idx];
    acc += x[j * INF_ + c];
  }
  h0[node * INF_ + c] = acc;
}

// ---- z1 = relu(h0 @ W1a + b1a), K=16, fp16 out ----
__global__ void k_gemm_k16(const float* __restrict__ h0, const float* __restrict__ W,
                           const float* __restrict__ bias, u16* __restrict__ out) {
  int r = blockIdx.y;
  int c = blockIdx.x * 256 + threadIdx.x;
  float acc = bias[c];
#pragma unroll
  for (int k = 0; k < INF_; ++k)
    acc = fmaf(h0[r * INF_ + k], W[k * DD + c], acc);
  out[r * DD + c] = f2h(fmaxf(acc, 0.f));
}

// ---- fused aggregation + BN-apply on [NODES,512] fp16 ----
// wave-per-node: 64 lanes x 8 ch (16 B/lane), 4 nodes/block, 2-way neighbor unroll.
// out[n][c] = sc[c]*(h[n][c] + sum_j h[j][c]) + (1+deg)*sh[c]
__global__ __launch_bounds__(256) void k_agg512_bn(const u16* __restrict__ h, const int* __restrict__ rowptr,
                                                   const int* __restrict__ col, const float* __restrict__ ss,
                                                   u16* __restrict__ out) {
  int lane = threadIdx.x & 63;
  int node = blockIdx.x * 4 + (threadIdx.x >> 6);   // grid 2500 x 4 = 10000 exact
  int c8 = lane * 8;
  const u16* hp = h + c8;
  float acc[8];
  {
    uint4 sv = *(const uint4*)(hp + (size_t)node * DD);
    acc[0] = h2f((u16)(sv.x & 0xffff)); acc[1] = h2f((u16)(sv.x >> 16));
    acc[2] = h2f((u16)(sv.y & 0xffff)); acc[3] = h2f((u16)(sv.y >> 16));
    acc[4] = h2f((u16)(sv.z & 0xffff)); acc[5] = h2f((u16)(sv.z >> 16));
    acc[6] = h2f((u16)(sv.w & 0xffff)); acc[7] = h2f((u16)(sv.w >> 16));
  }
  int r0 = rowptr[node], r1 = rowptr[node + 1];
  int idx = r0;
  for (; idx + 1 < r1; idx += 2) {
    int j0 = col[idx], j1 = col[idx + 1];
    uint4 a = *(const uint4*)(hp + (size_t)j0 * DD);
    uint4 b = *(const uint4*)(hp + (size_t)j1 * DD);
    add8(a, acc);
    add8(b, acc);
  }
  if (idx < r1) {
    int j = col[idx];
    uint4 a = *(const uint4*)(hp + (size_t)j * DD);
    add8(a, acc);
  }
  float n = (float)(r1 - r0 + 1);
  float4 sc0 = *(const float4*)(ss + c8);
  float4 sc1 = *(const float4*)(ss + c8 + 4);
  float4 sh0 = *(const float4*)(ss + DD + c8);
  float4 sh1 = *(const float4*)(ss + DD + c8 + 4);
  uint4 o;
  o.x = pk(sc0.x * acc[0] + n * sh0.x, sc0.y * acc[1] + n * sh0.y);
  o.y = pk(sc0.z * acc[2] + n * sh0.z, sc0.w * acc[3] + n * sh0.w);
  o.z = pk(sc1.x * acc[4] + n * sh1.x, sc1.y * acc[5] + n * sh1.y);
  o.w = pk(sc1.z * acc[6] + n * sh1.z, sc1.w * acc[7] + n * sh1.w);
  *(uint4*)(out + (size_t)node * DD + c8) = o;
}

// ---- MFMA GEMM: C[M,512] = relu(A[M,512](fp16) @ (Wh + Wl/1024)[512,512] + bias), fp16 out ----
// Wt layout: [n][k] (pre-transposed), hi plane then scaled-lo plane (+262144).
// BM=64 BN=128 BK=64; 256 thr = 4 waves, wave computes 32x64 via 2x4 16x16x32 MFMAs (x2 acc sets).
// STATS=1: per-column sum/sumsq of post-relu C -> stats[0..511 | 512..1023].
template <int STATS>
__global__ __launch_bounds__(256, 2) void mfma_gemm(
    const u16* __restrict__ A, const u16* __restrict__ Wt,
    const float* __restrict__ bias, u16* __restrict__ C, int M,
    float* __restrict__ stats) {
  __shared__ u16 lds[23040];           // 46080 B
  u16* As = lds;                       // [64][72]
  u16* Wh = lds + 4608;                // [128][72]
  u16* Wl = lds + 13824;               // [128][72]
  const int T = threadIdx.x;
  const int bm = blockIdx.y * 64;
  const int bn = blockIdx.x * 128;
  const int lane = T & 63;
  const int wave = T >> 6;
  const int wm = (wave & 1) * 32;
  const int wn = (wave >> 1) * 64;
  const int q = lane >> 4;
  const int r16 = lane & 15;

  f32x4 accH[2][4] = {};
  f32x4 accL[2][4] = {};

  for (int k0 = 0; k0 < 512; k0 += 64) {
    // stage A tile (guarded rows -> zeros)
#pragma unroll
    for (int p = 0; p < 2; ++p) {
      int c = T + 256 * p;
      int row = c >> 3, kc = c & 7;
      int grow = bm + row;
      uint4 z = make_uint4(0u, 0u, 0u, 0u);
      if (grow < M) z = *(const uint4*)(A + (size_t)grow * DD + k0 + kc * 8);
      *(uint4*)(As + row * 72 + kc * 8) = z;
    }
    // stage W tiles (hi + lo)
#pragma unroll
    for (int p = 0; p < 4; ++p) {
      int c = T + 256 * p;
      int row = c >> 3, kc = c & 7;
      const u16* srcp = Wt + (size_t)(bn + row) * DD + k0 + kc * 8;
      *(uint4*)(Wh + row * 72 + kc * 8) = *(const uint4*)(srcp);
      *(uint4*)(Wl + row * 72 + kc * 8) = *(const uint4*)(srcp + 262144);
    }
    __syncthreads();
#pragma unroll
    for (int ks = 0; ks < 2; ++ks) {
      int kb = ks * 32 + q * 8;
      f16x8 af[2], bh[4], bl[4];
#pragma unroll
      for (int mt = 0; mt < 2; ++mt)
        af[mt] = *(const f16x8*)(As + (wm + mt * 16 + r16) * 72 + kb);
#pragma unroll
      for (int nt = 0; nt < 4; ++nt) {
        bh[nt] = *(const f16x8*)(Wh + (wn + nt * 16 + r16) * 72 + kb);
        bl[nt] = *(const f16x8*)(Wl + (wn + nt * 16 + r16) * 72 + kb);
      }
#pragma unroll
      for (int mt = 0; mt < 2; ++mt)
#pragma unroll
        for (int nt = 0; nt < 4; ++nt) {
          accH[mt][nt] = __builtin_amdgcn_mfma_f32_16x16x32_f16(af[mt], bh[nt], accH[mt][nt], 0, 0, 0);
          accL[mt][nt] = __builtin_amdgcn_mfma_f32_16x16x32_f16(af[mt], bl[nt], accL[mt][nt], 0, 0, 0);
        }
    }
    __syncthreads();
  }

  // epilogue: combine hi/lo accumulators + bias + relu + fp16 store (+ optional BN stats)
  float colS[4] = {}, colQ[4] = {};
#pragma unroll
  for (int nt = 0; nt < 4; ++nt) {
    int n = bn + wn + nt * 16 + r16;
    float bv = bias[n];
#pragma unroll
    for (int mt = 0; mt < 2; ++mt) {
#pragma unroll
      for (int rr = 0; rr < 4; ++rr) {
        int row = bm + wm + mt * 16 + q * 4 + rr;
        if (row < M) {
          float v = fmaxf(accH[mt][nt][rr] + accL[mt][nt][rr] * (1.f / LOSCALE) + bv, 0.f);
          C[(size_t)row * DD + n] = f2h(v);
          if (STATS) { colS[nt] += v; colQ[nt] += v * v; }
        }
      }
    }
  }
  if (STATS) {
#pragma unroll
    for (int nt = 0; nt < 4; ++nt) {
      float s = colS[nt], qq = colQ[nt];
      s += __shfl_xor(s, 16); s += __shfl_xor(s, 32);
      qq += __shfl_xor(qq, 16); qq += __shfl_xor(qq, 32);
      if (q == 0) {
        int n = bn + wn + nt * 16 + r16;
        atomicAdd(&stats[n], s);
        atomicAdd(&stats[DD + n], qq);
      }
    }
  }
}

__global__ void k_bn_finalize(const float* __restrict__ sums, const float* __restrict__ gamma,
                              const float* __restrict__ beta, float* __restrict__ ss) {
  int c = threadIdx.x;  // block 512
  float mean = sums[c] * (1.f / NODES);
  float var = sums[DD + c] * (1.f / NODES) - mean * mean;
  float sc = gamma[c] * rsqrtf(var + BN_EPS);
  ss[c] = sc;
  ss[DD + c] = beta[c] - mean * sc;
}

// ---- pooling: graph boundaries via binary search (batch is sorted) ----
__global__ void k_bounds(const int* __restrict__ batch, int* __restrict__ gstart) {
  int g = threadIdx.x;  // block 128
  if (g > GRAPHS) return;
  if (g == GRAPHS) { gstart[GRAPHS] = NODES; return; }
  int lo = 0, hi = NODES;
  while (lo < hi) {
    int mid = (lo + hi) >> 1;
    if (batch[mid] < g) lo = mid + 1; else hi = mid;
  }
  gstart[g] = lo;
}

// ---- pooled mean per graph, no atomics: grid = GRAPHS, 128 thr x ushort4 ----
__global__ __launch_bounds__(128) void k_pool_mean(const u16* __restrict__ h, const int* __restrict__ gstart,
                                                   float* __restrict__ gsum) {
  int g = blockIdx.x;
  int c4 = threadIdx.x * 4;
  int r0 = gstart[g], r1 = gstart[g + 1];
  float4 acc = make_float4(0.f, 0.f, 0.f, 0.f);
  for (int r = r0; r < r1; ++r) {
    ushort4 v = *(const ushort4*)(h + (size_t)r * DD + c4);
    acc.x += h2f(v.x); acc.y += h2f(v.y); acc.z += h2f(v.z); acc.w += h2f(v.w);
  }
  float inv = 1.f / fmaxf((float)(r1 - r0), 1.f);
  acc.x *= inv; acc.y *= inv; acc.z *= inv; acc.w *= inv;
  *(float4*)(gsum + g * DD + c4) = acc;
}

// ---- head: feats = tanh(bn(pooled_mean) @ Wfc + bfc), layer-5 BN folded in ----
__global__ __launch_bounds__(512) void k_head(const float* __restrict__ gsum,
                                              const float* __restrict__ ss,
                                              const float* __restrict__ Wfc, const float* __restrict__ bfc,
                                              float* __restrict__ feats) {
  __shared__ float pv[512];
  int g = blockIdx.x, c = threadIdx.x;
  pv[c] = gsum[g * DD + c] * ss[c] + ss[DD + c];
  __syncthreads();
  float acc = bfc[c];
  for (int k = 0; k < DD; ++k)
    acc = fmaf(pv[k], Wfc[k * DD + c], acc);
  feats[g * DD + c] = tanhf(acc);
}

// ---- logits = feats @ Wlog + blog, out fp32 ----
__global__ void k_logits(const float* __restrict__ feats, const float* __restrict__ Wlog,
                         const float* __restrict__ blog, float* __restrict__ out) {
  int g = blockIdx.x, o = threadIdx.x;
  if (o >= NOUT) return;
  float acc = blog[o];
  const float* f = feats + g * DD;
  for (int k = 0; k < DD; ++k)
    acc = fmaf(f[k], Wlog[k * NOUT + o], acc);
  out[g * NOUT + o] = acc;
}

extern "C" void kernel_launch(void* const* d_in, const int* in_sizes, int n_in,
                              void* d_out, int out_size, void* d_ws, size_t ws_size,
                              hipStream_t stream) {
  const float* x = (const float*)d_in[0];
  const int* ei = (const int*)d_in[1];
  const int* batch = (const int*)d_in[2];
  const float* W1a = (const float*)d_in[3];
  const float* b1a = (const float*)d_in[4];
  const float* W1b = (const float*)d_in[5];
  const float* b1b = (const float*)d_in[6];
  const float* Wa = (const float*)d_in[7];
  const float* ba = (const float*)d_in[8];
  const float* Wb = (const float*)d_in[9];
  const float* bb = (const float*)d_in[10];
  const float* bng = (const float*)d_in[11];
  const float* bnb = (const float*)d_in[12];
  const float* Wfc = (const float*)d_in[13];
  const float* bfc = (const float*)d_in[14];
  const float* Wlog = (const float*)d_in[15];
  const float* blog = (const float*)d_in[16];
  float* out = (float*)d_out;

  const int* src = ei;
  const int* dstp = ei + EDGES;

  char* w = (char*)d_ws;
  int* rowptr  = (int*)(w);                 // 10001 i32
  int* cur     = (int*)(w + 40192);         // 10000 i32
  int* col     = (int*)(w + 80384);         // 160000 i32
  float* h0    = (float*)(w + 720384);      // 160000 f
  float* bns   = (float*)(w + 1360384);     // 5 x 1024 f
  float* bnss  = (float*)(w + 1380864);     // 5 x 1024 f
  float* gsum  = (float*)(w + 1401344);     // 32768 f (pooled means)
  int* gstart  = (int*)(w + 1532416);       // 65 i32 (pad to 512 B)
  float* feats = (float*)(w + 1532928);     // 32768 f
  u16* Wt      = (u16*)(w + 1664000);       // 9 x (hi 262144 + lo 262144) u16 = 9.44 MB
  u16* P0      = (u16*)(w + 11101184);      // 5,120,000 fp16
  u16* P1      = (u16*)(w + 21341184);      // 5,120,000 fp16 (end ~30.1 MB)

  // CSR build
  k_zero_i32<<<40, 256, 0, stream>>>(cur, NODES);
  k_count<<<625, 256, 0, stream>>>(dstp, cur);
  k_scan<<<1, 1024, 0, stream>>>(cur, rowptr);
  k_zero_i32<<<40, 256, 0, stream>>>(cur, NODES);
  k_fill<<<625, 256, 0, stream>>>(src, dstp, rowptr, cur, col);

  // zero BN stats accumulators (5 x 1024)
  k_zero_f32<<<20, 256, 0, stream>>>(bns, 5120);

  // weight transpose + hi/lo split (9 DxD matrices)
  k_wsplit<<<dim3(16, 16, 9), 256, 0, stream>>>(W1b, Wa, Wb, Wt);

  // layer 1
  k_agg16<<<625, 256, 0, stream>>>(x, rowptr, col, h0);
  k_gemm_k16<<<dim3(2, NODES), 256, 0, stream>>>(h0, W1a, b1a, P0);
  mfma_gemm<1><<<dim3(4, 157), 256, 0, stream>>>(P0, Wt, b1b, P1, NODES, bns);
  k_bn_finalize<<<1, 512, 0, stream>>>(bns, bng, bnb, bnss);

  // layers 2..5: H -> agg+bn -> T -> mfma(Wa) -> H -> mfma(Wb)+stats -> T
  u16* H = P1;
  u16* T = P0;
  for (int i = 0; i < 4; ++i) {
    k_agg512_bn<<<2500, 256, 0, stream>>>(H, rowptr, col, bnss + i * 1024, T);
    mfma_gemm<0><<<dim3(4, 157), 256, 0, stream>>>(T, Wt + (size_t)(1 + i) * 524288, ba + i * DD, H, NODES, nullptr);
    mfma_gemm<1><<<dim3(4, 157), 256, 0, stream>>>(H, Wt + (size_t)(5 + i) * 524288, bb + i * DD, T, NODES,
                                                   bns + (i + 1) * 1024);
    k_bn_finalize<<<1, 512, 0, stream>>>(bns + (i + 1) * 1024, bng + (i + 1) * DD, bnb + (i + 1) * DD,
                                         bnss + (i + 1) * 1024);
    u16* tmp = H; H = T; T = tmp;
  }

  // pooling (no atomics) + head
  k_bounds<<<1, 128, 0, stream>>>(batch, gstart);
  k_pool_mean<<<GRAPHS, 128, 0, stream>>>(H, gstart, gsum);
  k_head<<<GRAPHS, 512, 0, stream>>>(gsum, bnss + 4 * 1024, Wfc, bfc, feats);
  k_logits<<<GRAPHS, 64, 0, stream>>>(feats, Wlog, blog, out);
}

// Round 7
// 665.704 us; speedup vs baseline: 2.1240x; 1.0682x over previous
//
#include <hip/hip_runtime.h>

#define NODES 10000
#define EDGES 160000
#define INF_ 16
#define DD 512
#define GRAPHS 64
#define NOUT 18
#define BN_EPS 1e-5f
#define LOSCALE 1024.f

using u16 = unsigned short;
typedef __attribute__((ext_vector_type(8))) _Float16 f16x8;
typedef __attribute__((ext_vector_type(4))) float f32x4;

__device__ __forceinline__ float h2f(u16 u) {
  union { u16 u; _Float16 h; } v; v.u = u; return (float)v.h;
}
__device__ __forceinline__ u16 f2h(float f) {
  union { u16 u; _Float16 h; } v; v.h = (_Float16)f; return v.u;
}
__device__ __forceinline__ void add8(uint4 u, float* a) {
  a[0] += h2f((u16)(u.x & 0xffff)); a[1] += h2f((u16)(u.x >> 16));
  a[2] += h2f((u16)(u.y & 0xffff)); a[3] += h2f((u16)(u.y >> 16));
  a[4] += h2f((u16)(u.z & 0xffff)); a[5] += h2f((u16)(u.z >> 16));
  a[6] += h2f((u16)(u.w & 0xffff)); a[7] += h2f((u16)(u.w >> 16));
}
__device__ __forceinline__ unsigned int pk(float a, float b) {
  return (unsigned int)f2h(a) | ((unsigned int)f2h(b) << 16);
}

__global__ void k_zero_i32(int* p, int n) { int i = blockIdx.x * 256 + threadIdx.x; if (i < n) p[i] = 0; }
__global__ void k_zero_f32(float* p, int n) { int i = blockIdx.x * 256 + threadIdx.x; if (i < n) p[i] = 0.f; }

// ---- CSR build (dst-indexed): count -> scan -> fill ----
__global__ void k_count(const int* __restrict__ dst, int* __restrict__ cnt) {
  int e = blockIdx.x * 256 + threadIdx.x;
  if (e < EDGES) atomicAdd(&cnt[dst[e]], 1);
}

__global__ __launch_bounds__(1024) void k_scan(const int* __restrict__ cnt, int* __restrict__ rowptr) {
  __shared__ int s[1024];
  int t = threadIdx.x;
  int base = t * 10;
  int c[10]; int sum = 0;
#pragma unroll
  for (int i = 0; i < 10; ++i) { int idx = base + i; c[i] = (idx < NODES) ? cnt[idx] : 0; sum += c[i]; }
  s[t] = sum; __syncthreads();
  for (int off = 1; off < 1024; off <<= 1) {
    int v = s[t];
    int a = (t >= off) ? s[t - off] : 0;
    __syncthreads();
    s[t] = v + a;
    __syncthreads();
  }
  int run = (t == 0) ? 0 : s[t - 1];
#pragma unroll
  for (int i = 0; i < 10; ++i) { int idx = base + i; if (idx < NODES) rowptr[idx] = run; run += c[i]; }
  if (t == 1023) rowptr[NODES] = s[1023];
}

__global__ void k_fill(const int* __restrict__ src, const int* __restrict__ dst,
                       const int* __restrict__ rowptr, int* __restrict__ cur, int* __restrict__ col) {
  int e = blockIdx.x * 256 + threadIdx.x;
  if (e < EDGES) {
    int d = dst[e];
    int p = atomicAdd(&cur[d], 1);
    col[rowptr[d] + p] = src[e];
  }
}

// ---- W transpose + split into fp16 hi + fp16 (lo*1024) planes: Wt[n][k] = W[k][n] ----
// z: 0 -> W1b, 1..4 -> Wa[i], 5..8 -> Wb[i].
__global__ __launch_bounds__(256) void k_wsplit(const float* __restrict__ W1b, const float* __restrict__ Wa,
                                                const float* __restrict__ Wb, u16* __restrict__ Wt) {
  __shared__ float tile[32][33];
  int z = blockIdx.z;
  const float* src = (z == 0) ? W1b : (z <= 4 ? Wa + (z - 1) * DD * DD : Wb + (z - 5) * DD * DD);
  int kb = blockIdx.y * 32, nb = blockIdx.x * 32;
  int tx = threadIdx.x & 31, ty = threadIdx.x >> 5;  // 32 x 8
#pragma unroll
  for (int i = 0; i < 4; ++i)
    tile[ty + 8 * i][tx] = src[(kb + ty + 8 * i) * DD + nb + tx];
  __syncthreads();
  u16* hi = Wt + (size_t)z * 524288;
  u16* lo = hi + 262144;
#pragma unroll
  for (int i = 0; i < 4; ++i) {
    int n = nb + ty + 8 * i, k = kb + tx;
    float v = tile[tx][ty + 8 * i];
    u16 h = f2h(v);
    hi[n * DD + k] = h;
    lo[n * DD + k] = f2h((v - h2f(h)) * LOSCALE);
  }
}

// ---- layer-1 aggregation on [NODES,16] fp32 ----
__global__ void k_agg16(const float* __restrict__ x, const int* __restrict__ rowptr,
                        const int* __restrict__ col, float* __restrict__ h0) {
  int t = threadIdx.x;
  int node = blockIdx.x * 16 + (t >> 4);
  int c = t & 15;
  if (node >= NODES) return;
  float acc = x[node * INF_ + c];
  int r1 = rowptr[node + 1];
  for (int idx = rowptr[node]; idx < r1; ++idx) {
    int j = col[idx];
    acc += x[j * INF_ + c];
  }
  h0[node * INF_ + c] = acc;
}

// ---- z1 = relu(h0 @ W1a + b1a), K=16, fp16 out ----
__global__ void k_gemm_k16(const float* __restrict__ h0, const float* __restrict__ W,
                           const float* __restrict__ bias, u16* __restrict__ out) {
  int r = blockIdx.y;
  int c = blockIdx.x * 256 + threadIdx.x;
  float acc = bias[c];
#pragma unroll
  for (int k = 0; k < INF_; ++k)
    acc = fmaf(h0[r * INF_ + k], W[k * DD + c], acc);
  out[r * DD + c] = f2h(fmaxf(acc, 0.f));
}

// ---- fused aggregation + BN-finalize + BN-apply on [NODES,512] fp16 ----
// Per-thread preamble derives sc/sh for its 8 channels from raw stats (sum|sumsq),
// gamma, beta. out[n][c] = sc[c]*(h[n][c] + sum_j h[j][c]) + (1+deg)*sh[c]
__global__ __launch_bounds__(256) void k_agg512_bn(const u16* __restrict__ h, const int* __restrict__ rowptr,
                                                   const int* __restrict__ col, const float* __restrict__ stats,
                                                   const float* __restrict__ gamma, const float* __restrict__ beta,
                                                   u16* __restrict__ out) {
  int lane = threadIdx.x & 63;
  int node = blockIdx.x * 4 + (threadIdx.x >> 6);   // grid 2500 x 4 = 10000 exact
  int c8 = lane * 8;
  float sc[8], sh[8];
  {
    float4 s0 = *(const float4*)(stats + c8);
    float4 s1 = *(const float4*)(stats + c8 + 4);
    float4 q0 = *(const float4*)(stats + DD + c8);
    float4 q1 = *(const float4*)(stats + DD + c8 + 4);
    float4 g0 = *(const float4*)(gamma + c8);
    float4 g1 = *(const float4*)(gamma + c8 + 4);
    float4 b0 = *(const float4*)(beta + c8);
    float4 b1 = *(const float4*)(beta + c8 + 4);
    float ss[8] = {s0.x, s0.y, s0.z, s0.w, s1.x, s1.y, s1.z, s1.w};
    float qq[8] = {q0.x, q0.y, q0.z, q0.w, q1.x, q1.y, q1.z, q1.w};
    float gg[8] = {g0.x, g0.y, g0.z, g0.w, g1.x, g1.y, g1.z, g1.w};
    float bb[8] = {b0.x, b0.y, b0.z, b0.w, b1.x, b1.y, b1.z, b1.w};
#pragma unroll
    for (int k = 0; k < 8; ++k) {
      float mean = ss[k] * (1.f / NODES);
      float var = qq[k] * (1.f / NODES) - mean * mean;
      sc[k] = gg[k] * rsqrtf(var + BN_EPS);
      sh[k] = bb[k] - mean * sc[k];
    }
  }
  const u16* hp = h + c8;
  float acc[8];
  {
    uint4 sv = *(const uint4*)(hp + (size_t)node * DD);
    acc[0] = h2f((u16)(sv.x & 0xffff)); acc[1] = h2f((u16)(sv.x >> 16));
    acc[2] = h2f((u16)(sv.y & 0xffff)); acc[3] = h2f((u16)(sv.y >> 16));
    acc[4] = h2f((u16)(sv.z & 0xffff)); acc[5] = h2f((u16)(sv.z >> 16));
    acc[6] = h2f((u16)(sv.w & 0xffff)); acc[7] = h2f((u16)(sv.w >> 16));
  }
  int r0 = rowptr[node], r1 = rowptr[node + 1];
  int idx = r0;
  for (; idx + 1 < r1; idx += 2) {
    int j0 = col[idx], j1 = col[idx + 1];
    uint4 a = *(const uint4*)(hp + (size_t)j0 * DD);
    uint4 b = *(const uint4*)(hp + (size_t)j1 * DD);
    add8(a, acc);
    add8(b, acc);
  }
  if (idx < r1) {
    int j = col[idx];
    uint4 a = *(const uint4*)(hp + (size_t)j * DD);
    add8(a, acc);
  }
  float n = (float)(r1 - r0 + 1);
  uint4 o;
  o.x = pk(sc[0] * acc[0] + n * sh[0], sc[1] * acc[1] + n * sh[1]);
  o.y = pk(sc[2] * acc[2] + n * sh[2], sc[3] * acc[3] + n * sh[3]);
  o.z = pk(sc[4] * acc[4] + n * sh[4], sc[5] * acc[5] + n * sh[5]);
  o.w = pk(sc[6] * acc[6] + n * sh[6], sc[7] * acc[7] + n * sh[7]);
  *(uint4*)(out + (size_t)node * DD + c8) = o;
}

// ---- MFMA GEMM: C[M,512] = relu(A[M,512](fp16) @ (Wh + Wl/1024)[512,512] + bias), fp16 out ----
// Wt layout: [n][k] (pre-transposed), hi plane then scaled-lo plane (+262144).
// BM=64 BN=128 BK=64; 256 thr = 4 waves, wave computes 32x64 via 2x4 16x16x32 MFMAs (x2 acc sets).
// STATS=1: per-column sum/sumsq of post-relu C -> stats[0..511 | 512..1023].
template <int STATS>
__global__ __launch_bounds__(256, 2) void mfma_gemm(
    const u16* __restrict__ A, const u16* __restrict__ Wt,
    const float* __restrict__ bias, u16* __restrict__ C, int M,
    float* __restrict__ stats) {
  __shared__ u16 lds[23040];           // 46080 B
  u16* As = lds;                       // [64][72]
  u16* Wh = lds + 4608;                // [128][72]
  u16* Wl = lds + 13824;               // [128][72]
  const int T = threadIdx.x;
  const int bm = blockIdx.y * 64;
  const int bn = blockIdx.x * 128;
  const int lane = T & 63;
  const int wave = T >> 6;
  const int wm = (wave & 1) * 32;
  const int wn = (wave >> 1) * 64;
  const int q = lane >> 4;
  const int r16 = lane & 15;

  f32x4 accH[2][4] = {};
  f32x4 accL[2][4] = {};

  for (int k0 = 0; k0 < 512; k0 += 64) {
    // stage A tile (guarded rows -> zeros)
#pragma unroll
    for (int p = 0; p < 2; ++p) {
      int c = T + 256 * p;
      int row = c >> 3, kc = c & 7;
      int grow = bm + row;
      uint4 z = make_uint4(0u, 0u, 0u, 0u);
      if (grow < M) z = *(const uint4*)(A + (size_t)grow * DD + k0 + kc * 8);
      *(uint4*)(As + row * 72 + kc * 8) = z;
    }
    // stage W tiles (hi + lo)
#pragma unroll
    for (int p = 0; p < 4; ++p) {
      int c = T + 256 * p;
      int row = c >> 3, kc = c & 7;
      const u16* srcp = Wt + (size_t)(bn + row) * DD + k0 + kc * 8;
      *(uint4*)(Wh + row * 72 + kc * 8) = *(const uint4*)(srcp);
      *(uint4*)(Wl + row * 72 + kc * 8) = *(const uint4*)(srcp + 262144);
    }
    __syncthreads();
#pragma unroll
    for (int ks = 0; ks < 2; ++ks) {
      int kb = ks * 32 + q * 8;
      f16x8 af[2], bh[4], bl[4];
#pragma unroll
      for (int mt = 0; mt < 2; ++mt)
        af[mt] = *(const f16x8*)(As + (wm + mt * 16 + r16) * 72 + kb);
#pragma unroll
      for (int nt = 0; nt < 4; ++nt) {
        bh[nt] = *(const f16x8*)(Wh + (wn + nt * 16 + r16) * 72 + kb);
        bl[nt] = *(const f16x8*)(Wl + (wn + nt * 16 + r16) * 72 + kb);
      }
#pragma unroll
      for (int mt = 0; mt < 2; ++mt)
#pragma unroll
        for (int nt = 0; nt < 4; ++nt) {
          accH[mt][nt] = __builtin_amdgcn_mfma_f32_16x16x32_f16(af[mt], bh[nt], accH[mt][nt], 0, 0, 0);
          accL[mt][nt] = __builtin_amdgcn_mfma_f32_16x16x32_f16(af[mt], bl[nt], accL[mt][nt], 0, 0, 0);
        }
    }
    __syncthreads();
  }

  // epilogue: combine hi/lo accumulators + bias + relu + fp16 store (+ optional BN stats)
  float colS[4] = {}, colQ[4] = {};
#pragma unroll
  for (int nt = 0; nt < 4; ++nt) {
    int n = bn + wn + nt * 16 + r16;
    float bv = bias[n];
#pragma unroll
    for (int mt = 0; mt < 2; ++mt) {
#pragma unroll
      for (int rr = 0; rr < 4; ++rr) {
        int row = bm + wm + mt * 16 + q * 4 + rr;
        if (row < M) {
          float v = fmaxf(accH[mt][nt][rr] + accL[mt][nt][rr] * (1.f / LOSCALE) + bv, 0.f);
          C[(size_t)row * DD + n] = f2h(v);
          if (STATS) { colS[nt] += v; colQ[nt] += v * v; }
        }
      }
    }
  }
  if (STATS) {
#pragma unroll
    for (int nt = 0; nt < 4; ++nt) {
      float s = colS[nt], qq = colQ[nt];
      s += __shfl_xor(s, 16); s += __shfl_xor(s, 32);
      qq += __shfl_xor(qq, 16); qq += __shfl_xor(qq, 32);
      if (q == 0) {
        int n = bn + wn + nt * 16 + r16;
        atomicAdd(&stats[n], s);
        atomicAdd(&stats[DD + n], qq);
      }
    }
  }
}

// ---- pooling: graph boundaries via binary search (batch is sorted) ----
__global__ void k_bounds(const int* __restrict__ batch, int* __restrict__ gstart) {
  int g = threadIdx.x;  // block 128
  if (g > GRAPHS) return;
  if (g == GRAPHS) { gstart[GRAPHS] = NODES; return; }
  int lo = 0, hi = NODES;
  while (lo < hi) {
    int mid = (lo + hi) >> 1;
    if (batch[mid] < g) lo = mid + 1; else hi = mid;
  }
  gstart[g] = lo;
}

// ---- pooled partial sums: grid (GRAPHS, 8 slices), atomics into gsum ----
__global__ __launch_bounds__(128) void k_pool_part(const u16* __restrict__ h, const int* __restrict__ gstart,
                                                   float* __restrict__ gsum) {
  int g = blockIdx.x;
  int s = blockIdx.y;
  int c4 = threadIdx.x * 4;
  int r0 = gstart[g], r1 = gstart[g + 1];
  int cnt = r1 - r0;
  int len = (cnt + 7) >> 3;
  int rs = r0 + s * len;
  int re = min(rs + len, r1);
  if (rs >= re) return;
  float4 acc = make_float4(0.f, 0.f, 0.f, 0.f);
  for (int r = rs; r < re; ++r) {
    ushort4 v = *(const ushort4*)(h + (size_t)r * DD + c4);
    acc.x += h2f(v.x); acc.y += h2f(v.y); acc.z += h2f(v.z); acc.w += h2f(v.w);
  }
  atomicAdd(&gsum[g * DD + c4 + 0], acc.x);
  atomicAdd(&gsum[g * DD + c4 + 1], acc.y);
  atomicAdd(&gsum[g * DD + c4 + 2], acc.z);
  atomicAdd(&gsum[g * DD + c4 + 3], acc.w);
}

// ---- head: feats = tanh(bn(pooled_mean) @ Wfc + bfc); layer-5 BN finalize folded in ----
__global__ __launch_bounds__(512) void k_head(const float* __restrict__ gsum, const int* __restrict__ gstart,
                                              const float* __restrict__ stats,
                                              const float* __restrict__ gamma, const float* __restrict__ beta,
                                              const float* __restrict__ Wfc, const float* __restrict__ bfc,
                                              float* __restrict__ feats) {
  __shared__ float pv[512];
  int g = blockIdx.x, c = threadIdx.x;
  float inv = 1.f / fmaxf((float)(gstart[g + 1] - gstart[g]), 1.f);
  float mean = stats[c] * (1.f / NODES);
  float var = stats[DD + c] * (1.f / NODES) - mean * mean;
  float sc = gamma[c] * rsqrtf(var + BN_EPS);
  float sh = beta[c] - mean * sc;
  pv[c] = gsum[g * DD + c] * inv * sc + sh;
  __syncthreads();
  float acc = bfc[c];
  for (int k = 0; k < DD; ++k)
    acc = fmaf(pv[k], Wfc[k * DD + c], acc);
  feats[g * DD + c] = tanhf(acc);
}

// ---- logits = feats @ Wlog + blog, out fp32 ----
__global__ void k_logits(const float* __restrict__ feats, const float* __restrict__ Wlog,
                         const float* __restrict__ blog, float* __restrict__ out) {
  int g = blockIdx.x, o = threadIdx.x;
  if (o >= NOUT) return;
  float acc = blog[o];
  const float* f = feats + g * DD;
  for (int k = 0; k < DD; ++k)
    acc = fmaf(f[k], Wlog[k * NOUT + o], acc);
  out[g * NOUT + o] = acc;
}

extern "C" void kernel_launch(void* const* d_in, const int* in_sizes, int n_in,
                              void* d_out, int out_size, void* d_ws, size_t ws_size,
                              hipStream_t stream) {
  const float* x = (const float*)d_in[0];
  const int* ei = (const int*)d_in[1];
  const int* batch = (const int*)d_in[2];
  const float* W1a = (const float*)d_in[3];
  const float* b1a = (const float*)d_in[4];
  const float* W1b = (const float*)d_in[5];
  const float* b1b = (const float*)d_in[6];
  const float* Wa = (const float*)d_in[7];
  const float* ba = (const float*)d_in[8];
  const float* Wb = (const float*)d_in[9];
  const float* bb = (const float*)d_in[10];
  const float* bng = (const float*)d_in[11];
  const float* bnb = (const float*)d_in[12];
  const float* Wfc = (const float*)d_in[13];
  const float* bfc = (const float*)d_in[14];
  const float* Wlog = (const float*)d_in[15];
  const float* blog = (const float*)d_in[16];
  float* out = (float*)d_out;

  const int* src = ei;
  const int* dstp = ei + EDGES;

  char* w = (char*)d_ws;
  int* rowptr  = (int*)(w);                 // 10001 i32
  int* cur     = (int*)(w + 40192);         // 10000 i32
  int* col     = (int*)(w + 80384);         // 160000 i32
  float* h0    = (float*)(w + 720384);      // 160000 f
  float* bns   = (float*)(w + 1360384);     // 5 x 1024 f (raw stats)
  float* gsum  = (float*)(w + 1380864);     // 32768 f (contiguous after bns for joint zeroing)
  int* gstart  = (int*)(w + 1511936);       // 65 i32 (pad 512 B)
  float* feats = (float*)(w + 1512448);     // 32768 f
  u16* Wt      = (u16*)(w + 1643520);       // 9 x (hi 262144 + lo 262144) u16 = 9.44 MB
  u16* P0      = (u16*)(w + 11080704);      // 5,120,000 fp16
  u16* P1      = (u16*)(w + 21320704);      // 5,120,000 fp16 (end ~30.1 MB)

  // CSR build
  k_zero_i32<<<40, 256, 0, stream>>>(cur, NODES);
  k_count<<<625, 256, 0, stream>>>(dstp, cur);
  k_scan<<<1, 1024, 0, stream>>>(cur, rowptr);
  k_zero_i32<<<40, 256, 0, stream>>>(cur, NODES);
  k_fill<<<625, 256, 0, stream>>>(src, dstp, rowptr, cur, col);

  // zero bns (5x1024) + gsum (32768) in one pass: 37888 floats
  k_zero_f32<<<148, 256, 0, stream>>>(bns, 37888);

  // weight transpose + hi/lo split (9 DxD matrices)
  k_wsplit<<<dim3(16, 16, 9), 256, 0, stream>>>(W1b, Wa, Wb, Wt);

  // layer 1
  k_agg16<<<625, 256, 0, stream>>>(x, rowptr, col, h0);
  k_gemm_k16<<<dim3(2, NODES), 256, 0, stream>>>(h0, W1a, b1a, P0);
  mfma_gemm<1><<<dim3(4, 157), 256, 0, stream>>>(P0, Wt, b1b, P1, NODES, bns);

  // layers 2..5: H -> agg+bn(finalize folded) -> T -> mfma(Wa) -> H -> mfma(Wb)+stats -> T
  u16* H = P1;
  u16* T = P0;
  for (int i = 0; i < 4; ++i) {
    k_agg512_bn<<<2500, 256, 0, stream>>>(H, rowptr, col, bns + i * 1024, bng + i * DD, bnb + i * DD, T);
    mfma_gemm<0><<<dim3(4, 157), 256, 0, stream>>>(T, Wt + (size_t)(1 + i) * 524288, ba + i * DD, H, NODES, nullptr);
    mfma_gemm<1><<<dim3(4, 157), 256, 0, stream>>>(H, Wt + (size_t)(5 + i) * 524288, bb + i * DD, T, NODES,
                                                   bns + (i + 1) * 1024);
    u16* tmp = H; H = T; T = tmp;
  }

  // pooling (parallel partials) + head (layer-5 BN folded) + logits
  k_bounds<<<1, 128, 0, stream>>>(batch, gstart);
  k_pool_part<<<dim3(GRAPHS, 8), 128, 0, stream>>>(H, gstart, gsum);
  k_head<<<GRAPHS, 512, 0, stream>>>(gsum, gstart, bns + 4 * 1024, bng + 4 * DD, bnb + 4 * DD, Wfc, bfc, feats);
  k_logits<<<GRAPHS, 64, 0, stream>>>(feats, Wlog, blog, out);
}

// Round 8
// 634.248 us; speedup vs baseline: 2.2293x; 1.0496x over previous
//
#include <hip/hip_runtime.h>

#define NODES 10000
#define EDGES 160000
#define INF_ 16
#define DD 512
#define GRAPHS 64
#define NOUT 18
#define BN_EPS 1e-5f

using u16 = unsigned short;
typedef __attribute__((ext_vector_type(8))) _Float16 f16x8;
typedef __attribute__((ext_vector_type(4))) float f32x4;

__device__ __forceinline__ float h2f(u16 u) {
  union { u16 u; _Float16 h; } v; v.u = u; return (float)v.h;
}
__device__ __forceinline__ u16 f2h(float f) {
  union { u16 u; _Float16 h; } v; v.h = (_Float16)f; return v.u;
}
__device__ __forceinline__ void add8(uint4 u, float* a) {
  a[0] += h2f((u16)(u.x & 0xffff)); a[1] += h2f((u16)(u.x >> 16));
  a[2] += h2f((u16)(u.y & 0xffff)); a[3] += h2f((u16)(u.y >> 16));
  a[4] += h2f((u16)(u.z & 0xffff)); a[5] += h2f((u16)(u.z >> 16));
  a[6] += h2f((u16)(u.w & 0xffff)); a[7] += h2f((u16)(u.w >> 16));
}
__device__ __forceinline__ unsigned int pk(float a, float b) {
  return (unsigned int)f2h(a) | ((unsigned int)f2h(b) << 16);
}

__global__ void k_zero_i32(int* p, int n) { int i = blockIdx.x * 256 + threadIdx.x; if (i < n) p[i] = 0; }
__global__ void k_zero_f32(float* p, int n) { int i = blockIdx.x * 256 + threadIdx.x; if (i < n) p[i] = 0.f; }

// ---- CSR build (dst-indexed): count -> scan -> fill ----
__global__ void k_count(const int* __restrict__ dst, int* __restrict__ cnt) {
  int e = blockIdx.x * 256 + threadIdx.x;
  if (e < EDGES) atomicAdd(&cnt[dst[e]], 1);
}

__global__ __launch_bounds__(1024) void k_scan(const int* __restrict__ cnt, int* __restrict__ rowptr) {
  __shared__ int s[1024];
  int t = threadIdx.x;
  int base = t * 10;
  int c[10]; int sum = 0;
#pragma unroll
  for (int i = 0; i < 10; ++i) { int idx = base + i; c[i] = (idx < NODES) ? cnt[idx] : 0; sum += c[i]; }
  s[t] = sum; __syncthreads();
  for (int off = 1; off < 1024; off <<= 1) {
    int v = s[t];
    int a = (t >= off) ? s[t - off] : 0;
    __syncthreads();
    s[t] = v + a;
    __syncthreads();
  }
  int run = (t == 0) ? 0 : s[t - 1];
#pragma unroll
  for (int i = 0; i < 10; ++i) { int idx = base + i; if (idx < NODES) rowptr[idx] = run; run += c[i]; }
  if (t == 1023) rowptr[NODES] = s[1023];
}

__global__ void k_fill(const int* __restrict__ src, const int* __restrict__ dst,
                       const int* __restrict__ rowptr, int* __restrict__ cur, int* __restrict__ col) {
  int e = blockIdx.x * 256 + threadIdx.x;
  if (e < EDGES) {
    int d = dst[e];
    int p = atomicAdd(&cur[d], 1);
    col[rowptr[d] + p] = src[e];
  }
}

// ---- W transpose to fp16 [n][k]: Wt[n][k] = W[k][n] ----
// z: 0 -> W1b, 1..4 -> Wa[i], 5..8 -> Wb[i]. 262144 u16 per matrix.
__global__ __launch_bounds__(256) void k_wsplit(const float* __restrict__ W1b, const float* __restrict__ Wa,
                                                const float* __restrict__ Wb, u16* __restrict__ Wt) {
  __shared__ float tile[32][33];
  int z = blockIdx.z;
  const float* src = (z == 0) ? W1b : (z <= 4 ? Wa + (z - 1) * DD * DD : Wb + (z - 5) * DD * DD);
  int kb = blockIdx.y * 32, nb = blockIdx.x * 32;
  int tx = threadIdx.x & 31, ty = threadIdx.x >> 5;  // 32 x 8
#pragma unroll
  for (int i = 0; i < 4; ++i)
    tile[ty + 8 * i][tx] = src[(kb + ty + 8 * i) * DD + nb + tx];
  __syncthreads();
  u16* hi = Wt + (size_t)z * 262144;
#pragma unroll
  for (int i = 0; i < 4; ++i) {
    int n = nb + ty + 8 * i, k = kb + tx;
    hi[n * DD + k] = f2h(tile[tx][ty + 8 * i]);
  }
}

// ---- layer-1 aggregation on [NODES,16] fp32 ----
__global__ void k_agg16(const float* __restrict__ x, const int* __restrict__ rowptr,
                        const int* __restrict__ col, float* __restrict__ h0) {
  int t = threadIdx.x;
  int node = blockIdx.x * 16 + (t >> 4);
  int c = t & 15;
  if (node >= NODES) return;
  float acc = x[node * INF_ + c];
  int r1 = rowptr[node + 1];
  for (int idx = rowptr[node]; idx < r1; ++idx) {
    int j = col[idx];
    acc += x[j * INF_ + c];
  }
  h0[node * INF_ + c] = acc;
}

// ---- z1 = relu(h0 @ W1a + b1a), K=16, fp16 out ----
__global__ void k_gemm_k16(const float* __restrict__ h0, const float* __restrict__ W,
                           const float* __restrict__ bias, u16* __restrict__ out) {
  int r = blockIdx.y;
  int c = blockIdx.x * 256 + threadIdx.x;
  float acc = bias[c];
#pragma unroll
  for (int k = 0; k < INF_; ++k)
    acc = fmaf(h0[r * INF_ + k], W[k * DD + c], acc);
  out[r * DD + c] = f2h(fmaxf(acc, 0.f));
}

// ---- fused aggregation + BN-finalize + BN-apply on [NODES,512] fp16 ----
__global__ __launch_bounds__(256) void k_agg512_bn(const u16* __restrict__ h, const int* __restrict__ rowptr,
                                                   const int* __restrict__ col, const float* __restrict__ stats,
                                                   const float* __restrict__ gamma, const float* __restrict__ beta,
                                                   u16* __restrict__ out) {
  int lane = threadIdx.x & 63;
  int node = blockIdx.x * 4 + (threadIdx.x >> 6);   // grid 2500 x 4 = 10000 exact
  int c8 = lane * 8;
  float sc[8], sh[8];
  {
    float4 s0 = *(const float4*)(stats + c8);
    float4 s1 = *(const float4*)(stats + c8 + 4);
    float4 q0 = *(const float4*)(stats + DD + c8);
    float4 q1 = *(const float4*)(stats + DD + c8 + 4);
    float4 g0 = *(const float4*)(gamma + c8);
    float4 g1 = *(const float4*)(gamma + c8 + 4);
    float4 b0 = *(const float4*)(beta + c8);
    float4 b1 = *(const float4*)(beta + c8 + 4);
    float ss[8] = {s0.x, s0.y, s0.z, s0.w, s1.x, s1.y, s1.z, s1.w};
    float qq[8] = {q0.x, q0.y, q0.z, q0.w, q1.x, q1.y, q1.z, q1.w};
    float gg[8] = {g0.x, g0.y, g0.z, g0.w, g1.x, g1.y, g1.z, g1.w};
    float bb[8] = {b0.x, b0.y, b0.z, b0.w, b1.x, b1.y, b1.z, b1.w};
#pragma unroll
    for (int k = 0; k < 8; ++k) {
      float mean = ss[k] * (1.f / NODES);
      float var = qq[k] * (1.f / NODES) - mean * mean;
      sc[k] = gg[k] * rsqrtf(var + BN_EPS);
      sh[k] = bb[k] - mean * sc[k];
    }
  }
  const u16* hp = h + c8;
  float acc[8];
  {
    uint4 sv = *(const uint4*)(hp + (size_t)node * DD);
    acc[0] = h2f((u16)(sv.x & 0xffff)); acc[1] = h2f((u16)(sv.x >> 16));
    acc[2] = h2f((u16)(sv.y & 0xffff)); acc[3] = h2f((u16)(sv.y >> 16));
    acc[4] = h2f((u16)(sv.z & 0xffff)); acc[5] = h2f((u16)(sv.z >> 16));
    acc[6] = h2f((u16)(sv.w & 0xffff)); acc[7] = h2f((u16)(sv.w >> 16));
  }
  int r0 = rowptr[node], r1 = rowptr[node + 1];
  int idx = r0;
  for (; idx + 1 < r1; idx += 2) {
    int j0 = col[idx], j1 = col[idx + 1];
    uint4 a = *(const uint4*)(hp + (size_t)j0 * DD);
    uint4 b = *(const uint4*)(hp + (size_t)j1 * DD);
    add8(a, acc);
    add8(b, acc);
  }
  if (idx < r1) {
    int j = col[idx];
    uint4 a = *(const uint4*)(hp + (size_t)j * DD);
    add8(a, acc);
  }
  float n = (float)(r1 - r0 + 1);
  uint4 o;
  o.x = pk(sc[0] * acc[0] + n * sh[0], sc[1] * acc[1] + n * sh[1]);
  o.y = pk(sc[2] * acc[2] + n * sh[2], sc[3] * acc[3] + n * sh[3]);
  o.z = pk(sc[4] * acc[4] + n * sh[4], sc[5] * acc[5] + n * sh[5]);
  o.w = pk(sc[6] * acc[6] + n * sh[6], sc[7] * acc[7] + n * sh[7]);
  *(uint4*)(out + (size_t)node * DD + c8) = o;
}

// ---- MFMA GEMM: C[M,512] = relu(A[M,512](fp16) @ W[512,512](fp16,[n][k]) + bias), fp16 out ----
// BM=64 BN=128 BK=64; 256 thr = 4 waves, wave computes 32x64 via 2x4 16x16x32 MFMAs.
// Register-prefetch pipeline: iter k+1's global loads issue during iter k's compute.
// STATS=1: per-column sum/sumsq of post-relu C -> stats[0..511 | 512..1023].
template <int STATS>
__global__ __launch_bounds__(256, 4) void mfma_gemm(
    const u16* __restrict__ A, const u16* __restrict__ Wt,
    const float* __restrict__ bias, u16* __restrict__ C, int M,
    float* __restrict__ stats) {
  __shared__ u16 lds[13824];           // 27648 B
  u16* As = lds;                       // [64][72]
  u16* Wh = lds + 4608;                // [128][72]
  const int T = threadIdx.x;
  const int bm = blockIdx.y * 64;
  const int bn = blockIdx.x * 128;
  const int lane = T & 63;
  const int wave = T >> 6;
  const int wm = (wave & 1) * 32;
  const int wn = (wave >> 1) * 64;
  const int q = lane >> 4;
  const int r16 = lane & 15;

  const int arow0 = bm + (T >> 3);           // rows for A staging (p=0); p=1 adds 32
  const int akc = (T & 7) * 8;
  f32x4 acc[2][4] = {};

  uint4 ra[2], rw[4];
  // prefetch k0 = 0
#pragma unroll
  for (int p = 0; p < 2; ++p) {
    int grow = arow0 + p * 32;
    ra[p] = make_uint4(0u, 0u, 0u, 0u);
    if (grow < M) ra[p] = *(const uint4*)(A + (size_t)grow * DD + akc);
  }
#pragma unroll
  for (int p = 0; p < 4; ++p) {
    int row = (T + 256 * p) >> 3;
    rw[p] = *(const uint4*)(Wt + (size_t)(bn + row) * DD + akc);
  }

  for (int k0 = 0; k0 < 512; k0 += 64) {
    // LDS write from prefetch regs
#pragma unroll
    for (int p = 0; p < 2; ++p) {
      int row = (T >> 3) + p * 32;
      *(uint4*)(As + row * 72 + akc) = ra[p];
    }
#pragma unroll
    for (int p = 0; p < 4; ++p) {
      int row = (T + 256 * p) >> 3;
      *(uint4*)(Wh + row * 72 + akc) = rw[p];
    }
    __syncthreads();
    // prefetch next tile while computing this one
    if (k0 + 64 < 512) {
      int kn = k0 + 64;
#pragma unroll
      for (int p = 0; p < 2; ++p) {
        int grow = arow0 + p * 32;
        ra[p] = make_uint4(0u, 0u, 0u, 0u);
        if (grow < M) ra[p] = *(const uint4*)(A + (size_t)grow * DD + kn + akc);
      }
#pragma unroll
      for (int p = 0; p < 4; ++p) {
        int row = (T + 256 * p) >> 3;
        rw[p] = *(const uint4*)(Wt + (size_t)(bn + row) * DD + kn + akc);
      }
    }
#pragma unroll
    for (int ks = 0; ks < 2; ++ks) {
      int kb = ks * 32 + q * 8;
      f16x8 af[2], bh[4];
#pragma unroll
      for (int mt = 0; mt < 2; ++mt)
        af[mt] = *(const f16x8*)(As + (wm + mt * 16 + r16) * 72 + kb);
#pragma unroll
      for (int nt = 0; nt < 4; ++nt)
        bh[nt] = *(const f16x8*)(Wh + (wn + nt * 16 + r16) * 72 + kb);
#pragma unroll
      for (int mt = 0; mt < 2; ++mt)
#pragma unroll
        for (int nt = 0; nt < 4; ++nt)
          acc[mt][nt] = __builtin_amdgcn_mfma_f32_16x16x32_f16(af[mt], bh[nt], acc[mt][nt], 0, 0, 0);
    }
    __syncthreads();
  }

  // epilogue: bias + relu + fp16 store (+ optional BN stats)
  float colS[4] = {}, colQ[4] = {};
#pragma unroll
  for (int nt = 0; nt < 4; ++nt) {
    int n = bn + wn + nt * 16 + r16;
    float bv = bias[n];
#pragma unroll
    for (int mt = 0; mt < 2; ++mt) {
#pragma unroll
      for (int rr = 0; rr < 4; ++rr) {
        int row = bm + wm + mt * 16 + q * 4 + rr;
        if (row < M) {
          float v = fmaxf(acc[mt][nt][rr] + bv, 0.f);
          C[(size_t)row * DD + n] = f2h(v);
          if (STATS) { colS[nt] += v; colQ[nt] += v * v; }
        }
      }
    }
  }
  if (STATS) {
#pragma unroll
    for (int nt = 0; nt < 4; ++nt) {
      float s = colS[nt], qq = colQ[nt];
      s += __shfl_xor(s, 16); s += __shfl_xor(s, 32);
      qq += __shfl_xor(qq, 16); qq += __shfl_xor(qq, 32);
      if (q == 0) {
        int n = bn + wn + nt * 16 + r16;
        atomicAdd(&stats[n], s);
        atomicAdd(&stats[DD + n], qq);
      }
    }
  }
}

// ---- pooling: graph boundaries via binary search (batch is sorted) ----
__global__ void k_bounds(const int* __restrict__ batch, int* __restrict__ gstart) {
  int g = threadIdx.x;  // block 128
  if (g > GRAPHS) return;
  if (g == GRAPHS) { gstart[GRAPHS] = NODES; return; }
  int lo = 0, hi = NODES;
  while (lo < hi) {
    int mid = (lo + hi) >> 1;
    if (batch[mid] < g) lo = mid + 1; else hi = mid;
  }
  gstart[g] = lo;
}

// ---- pooled partial sums: grid (GRAPHS, 8 slices), atomics into gsum ----
__global__ __launch_bounds__(128) void k_pool_part(const u16* __restrict__ h, const int* __restrict__ gstart,
                                                   float* __restrict__ gsum) {
  int g = blockIdx.x;
  int s = blockIdx.y;
  int c4 = threadIdx.x * 4;
  int r0 = gstart[g], r1 = gstart[g + 1];
  int cnt = r1 - r0;
  int len = (cnt + 7) >> 3;
  int rs = r0 + s * len;
  int re = min(rs + len, r1);
  if (rs >= re) return;
  float4 acc = make_float4(0.f, 0.f, 0.f, 0.f);
  for (int r = rs; r < re; ++r) {
    ushort4 v = *(const ushort4*)(h + (size_t)r * DD + c4);
    acc.x += h2f(v.x); acc.y += h2f(v.y); acc.z += h2f(v.z); acc.w += h2f(v.w);
  }
  atomicAdd(&gsum[g * DD + c4 + 0], acc.x);
  atomicAdd(&gsum[g * DD + c4 + 1], acc.y);
  atomicAdd(&gsum[g * DD + c4 + 2], acc.z);
  atomicAdd(&gsum[g * DD + c4 + 3], acc.w);
}

// ---- head: feats = tanh(bn(pooled_mean) @ Wfc + bfc); layer-5 BN finalize folded in ----
__global__ __launch_bounds__(512) void k_head(const float* __restrict__ gsum, const int* __restrict__ gstart,
                                              const float* __restrict__ stats,
                                              const float* __restrict__ gamma, const float* __restrict__ beta,
                                              const float* __restrict__ Wfc, const float* __restrict__ bfc,
                                              float* __restrict__ feats) {
  __shared__ float pv[512];
  int g = blockIdx.x, c = threadIdx.x;
  float inv = 1.f / fmaxf((float)(gstart[g + 1] - gstart[g]), 1.f);
  float mean = stats[c] * (1.f / NODES);
  float var = stats[DD + c] * (1.f / NODES) - mean * mean;
  float sc = gamma[c] * rsqrtf(var + BN_EPS);
  float sh = beta[c] - mean * sc;
  pv[c] = gsum[g * DD + c] * inv * sc + sh;
  __syncthreads();
  float acc = bfc[c];
  for (int k = 0; k < DD; ++k)
    acc = fmaf(pv[k], Wfc[k * DD + c], acc);
  feats[g * DD + c] = tanhf(acc);
}

// ---- logits = feats @ Wlog + blog, out fp32 ----
__global__ void k_logits(const float* __restrict__ feats, const float* __restrict__ Wlog,
                         const float* __restrict__ blog, float* __restrict__ out) {
  int g = blockIdx.x, o = threadIdx.x;
  if (o >= NOUT) return;
  float acc = blog[o];
  const float* f = feats + g * DD;
  for (int k = 0; k < DD; ++k)
    acc = fmaf(f[k], Wlog[k * NOUT + o], acc);
  out[g * NOUT + o] = acc;
}

extern "C" void kernel_launch(void* const* d_in, const int* in_sizes, int n_in,
                              void* d_out, int out_size, void* d_ws, size_t ws_size,
                              hipStream_t stream) {
  const float* x = (const float*)d_in[0];
  const int* ei = (const int*)d_in[1];
  const int* batch = (const int*)d_in[2];
  const float* W1a = (const float*)d_in[3];
  const float* b1a = (const float*)d_in[4];
  const float* W1b = (const float*)d_in[5];
  const float* b1b = (const float*)d_in[6];
  const float* Wa = (const float*)d_in[7];
  const float* ba = (const float*)d_in[8];
  const float* Wb = (const float*)d_in[9];
  const float* bb = (const float*)d_in[10];
  const float* bng = (const float*)d_in[11];
  const float* bnb = (const float*)d_in[12];
  const float* Wfc = (const float*)d_in[13];
  const float* bfc = (const float*)d_in[14];
  const float* Wlog = (const float*)d_in[15];
  const float* blog = (const float*)d_in[16];
  float* out = (float*)d_out;

  const int* src = ei;
  const int* dstp = ei + EDGES;

  char* w = (char*)d_ws;
  int* rowptr  = (int*)(w);                 // 10001 i32
  int* cur     = (int*)(w + 40192);         // 10000 i32
  int* col     = (int*)(w + 80384);         // 160000 i32
  float* h0    = (float*)(w + 720384);      // 160000 f
  float* bns   = (float*)(w + 1360384);     // 5 x 1024 f (raw stats)
  float* gsum  = (float*)(w + 1380864);     // 32768 f (contiguous after bns for joint zeroing)
  int* gstart  = (int*)(w + 1511936);       // 65 i32 (pad 512 B)
  float* feats = (float*)(w + 1512448);     // 32768 f
  u16* Wt      = (u16*)(w + 1643520);       // 9 x 262144 u16 = 4.72 MB
  u16* P0      = (u16*)(w + 6362112);       // 5,120,000 fp16
  u16* P1      = (u16*)(w + 16602112);      // 5,120,000 fp16 (end ~26.9 MB)

  // CSR build
  k_zero_i32<<<40, 256, 0, stream>>>(cur, NODES);
  k_count<<<625, 256, 0, stream>>>(dstp, cur);
  k_scan<<<1, 1024, 0, stream>>>(cur, rowptr);
  k_zero_i32<<<40, 256, 0, stream>>>(cur, NODES);
  k_fill<<<625, 256, 0, stream>>>(src, dstp, rowptr, cur, col);

  // zero bns (5x1024) + gsum (32768) in one pass: 37888 floats
  k_zero_f32<<<148, 256, 0, stream>>>(bns, 37888);

  // weight transpose to fp16 (9 DxD matrices)
  k_wsplit<<<dim3(16, 16, 9), 256, 0, stream>>>(W1b, Wa, Wb, Wt);

  // layer 1
  k_agg16<<<625, 256, 0, stream>>>(x, rowptr, col, h0);
  k_gemm_k16<<<dim3(2, NODES), 256, 0, stream>>>(h0, W1a, b1a, P0);
  mfma_gemm<1><<<dim3(4, 157), 256, 0, stream>>>(P0, Wt, b1b, P1, NODES, bns);

  // layers 2..5: H -> agg+bn(finalize folded) -> T -> mfma(Wa) -> H -> mfma(Wb)+stats -> T
  u16* H = P1;
  u16* T = P0;
  for (int i = 0; i < 4; ++i) {
    k_agg512_bn<<<2500, 256, 0, stream>>>(H, rowptr, col, bns + i * 1024, bng + i * DD, bnb + i * DD, T);
    mfma_gemm<0><<<dim3(4, 157), 256, 0, stream>>>(T, Wt + (size_t)(1 + i) * 262144, ba + i * DD, H, NODES, nullptr);
    mfma_gemm<1><<<dim3(4, 157), 256, 0, stream>>>(H, Wt + (size_t)(5 + i) * 262144, bb + i * DD, T, NODES,
                                                   bns + (i + 1) * 1024);
    u16* tmp = H; H = T; T = tmp;
  }

  // pooling (parallel partials) + head (layer-5 BN folded) + logits
  k_bounds<<<1, 128, 0, stream>>>(batch, gstart);
  k_pool_part<<<dim3(GRAPHS, 8), 128, 0, stream>>>(H, gstart, gsum);
  k_head<<<GRAPHS, 512, 0, stream>>>(gsum, gstart, bns + 4 * 1024, bng + 4 * DD, bnb + 4 * DD, Wfc, bfc, feats);
  k_logits<<<GRAPHS, 64, 0, stream>>>(feats, Wlog, blog, out);
}

// Round 9
// 633.739 us; speedup vs baseline: 2.2311x; 1.0008x over previous
//
#include <hip/hip_runtime.h>

#define NODES 10000
#define EDGES 160000
#define INF_ 16
#define DD 512
#define GRAPHS 64
#define NOUT 18
#define BN_EPS 1e-5f
#define NBUCK 8

using u16 = unsigned short;
typedef __attribute__((ext_vector_type(8))) _Float16 f16x8;
typedef __attribute__((ext_vector_type(4))) float f32x4;

__device__ __forceinline__ float h2f(u16 u) {
  union { u16 u; _Float16 h; } v; v.u = u; return (float)v.h;
}
__device__ __forceinline__ u16 f2h(float f) {
  union { u16 u; _Float16 h; } v; v.h = (_Float16)f; return v.u;
}
__device__ __forceinline__ void add8(uint4 u, float* a) {
  a[0] += h2f((u16)(u.x & 0xffff)); a[1] += h2f((u16)(u.x >> 16));
  a[2] += h2f((u16)(u.y & 0xffff)); a[3] += h2f((u16)(u.y >> 16));
  a[4] += h2f((u16)(u.z & 0xffff)); a[5] += h2f((u16)(u.z >> 16));
  a[6] += h2f((u16)(u.w & 0xffff)); a[7] += h2f((u16)(u.w >> 16));
}
__device__ __forceinline__ unsigned int pk(float a, float b) {
  return (unsigned int)f2h(a) | ((unsigned int)f2h(b) << 16);
}

__global__ void k_zero_i32(int* p, int n) { int i = blockIdx.x * 256 + threadIdx.x; if (i < n) p[i] = 0; }
__global__ void k_zero_f32(float* p, int n) { int i = blockIdx.x * 256 + threadIdx.x; if (i < n) p[i] = 0.f; }

// ---- CSR build (dst-indexed): count -> scan -> fill ----
__global__ void k_count(const int* __restrict__ dst, int* __restrict__ cnt) {
  int e = blockIdx.x * 256 + threadIdx.x;
  if (e < EDGES) atomicAdd(&cnt[dst[e]], 1);
}

__global__ __launch_bounds__(1024) void k_scan(const int* __restrict__ cnt, int* __restrict__ rowptr) {
  __shared__ int s[1024];
  int t = threadIdx.x;
  int base = t * 10;
  int c[10]; int sum = 0;
#pragma unroll
  for (int i = 0; i < 10; ++i) { int idx = base + i; c[i] = (idx < NODES) ? cnt[idx] : 0; sum += c[i]; }
  s[t] = sum; __syncthreads();
  for (int off = 1; off < 1024; off <<= 1) {
    int v = s[t];
    int a = (t >= off) ? s[t - off] : 0;
    __syncthreads();
    s[t] = v + a;
    __syncthreads();
  }
  int run = (t == 0) ? 0 : s[t - 1];
#pragma unroll
  for (int i = 0; i < 10; ++i) { int idx = base + i; if (idx < NODES) rowptr[idx] = run; run += c[i]; }
  if (t == 1023) rowptr[NODES] = s[1023];
}

__global__ void k_fill(const int* __restrict__ src, const int* __restrict__ dst,
                       const int* __restrict__ rowptr, int* __restrict__ cur, int* __restrict__ col) {
  int e = blockIdx.x * 256 + threadIdx.x;
  if (e < EDGES) {
    int d = dst[e];
    int p = atomicAdd(&cur[d], 1);
    col[rowptr[d] + p] = src[e];
  }
}

// ---- W transpose to fp16 [n][k]: Wt[n][k] = W[k][n] ----
__global__ __launch_bounds__(256) void k_wsplit(const float* __restrict__ W1b, const float* __restrict__ Wa,
                                                const float* __restrict__ Wb, u16* __restrict__ Wt) {
  __shared__ float tile[32][33];
  int z = blockIdx.z;
  const float* src = (z == 0) ? W1b : (z <= 4 ? Wa + (z - 1) * DD * DD : Wb + (z - 5) * DD * DD);
  int kb = blockIdx.y * 32, nb = blockIdx.x * 32;
  int tx = threadIdx.x & 31, ty = threadIdx.x >> 5;  // 32 x 8
#pragma unroll
  for (int i = 0; i < 4; ++i)
    tile[ty + 8 * i][tx] = src[(kb + ty + 8 * i) * DD + nb + tx];
  __syncthreads();
  u16* hi = Wt + (size_t)z * 262144;
#pragma unroll
  for (int i = 0; i < 4; ++i) {
    int n = nb + ty + 8 * i, k = kb + tx;
    hi[n * DD + k] = f2h(tile[tx][ty + 8 * i]);
  }
}

// ---- layer-1 aggregation on [NODES,16] fp32 ----
__global__ void k_agg16(const float* __restrict__ x, const int* __restrict__ rowptr,
                        const int* __restrict__ col, float* __restrict__ h0) {
  int t = threadIdx.x;
  int node = blockIdx.x * 16 + (t >> 4);
  int c = t & 15;
  if (node >= NODES) return;
  float acc = x[node * INF_ + c];
  int r1 = rowptr[node + 1];
  for (int idx = rowptr[node]; idx < r1; ++idx) {
    int j = col[idx];
    acc += x[j * INF_ + c];
  }
  h0[node * INF_ + c] = acc;
}

// ---- z1 = relu(h0 @ W1a + b1a), K=16, fp16 out ----
__global__ void k_gemm_k16(const float* __restrict__ h0, const float* __restrict__ W,
                           const float* __restrict__ bias, u16* __restrict__ out) {
  int r = blockIdx.y;
  int c = blockIdx.x * 256 + threadIdx.x;
  float acc = bias[c];
#pragma unroll
  for (int k = 0; k < INF_; ++k)
    acc = fmaf(h0[r * INF_ + k], W[k * DD + c], acc);
  out[r * DD + c] = f2h(fmaxf(acc, 0.f));
}

// ---- fused aggregation + BN(finalize from bucketed stats) + apply, [NODES,512] fp16 ----
// stats: NBUCK buckets of 1024 floats (sum[0..511] | sumsq[512..1023]).
__global__ __launch_bounds__(256) void k_agg512_bn(const u16* __restrict__ h, const int* __restrict__ rowptr,
                                                   const int* __restrict__ col, const float* __restrict__ stats,
                                                   const float* __restrict__ gamma, const float* __restrict__ beta,
                                                   u16* __restrict__ out) {
  __shared__ float ssc[512], ssh[512];
  int t = threadIdx.x;
#pragma unroll
  for (int r = 0; r < 2; ++r) {
    int c = t + r * 256;
    float s = 0.f, qv = 0.f;
#pragma unroll
    for (int b = 0; b < NBUCK; ++b) {
      s += stats[b * 1024 + c];
      qv += stats[b * 1024 + 512 + c];
    }
    float mean = s * (1.f / NODES);
    float var = qv * (1.f / NODES) - mean * mean;
    float sc = gamma[c] * rsqrtf(var + BN_EPS);
    ssc[c] = sc;
    ssh[c] = beta[c] - mean * sc;
  }
  __syncthreads();

  int lane = t & 63;
  int node = blockIdx.x * 4 + (t >> 6);   // grid 2500 x 4 = 10000 exact
  int c8 = lane * 8;
  float sc[8], sh[8];
#pragma unroll
  for (int k = 0; k < 8; ++k) { sc[k] = ssc[c8 + k]; sh[k] = ssh[c8 + k]; }

  const u16* hp = h + c8;
  float acc[8];
  {
    uint4 sv = *(const uint4*)(hp + (size_t)node * DD);
    acc[0] = h2f((u16)(sv.x & 0xffff)); acc[1] = h2f((u16)(sv.x >> 16));
    acc[2] = h2f((u16)(sv.y & 0xffff)); acc[3] = h2f((u16)(sv.y >> 16));
    acc[4] = h2f((u16)(sv.z & 0xffff)); acc[5] = h2f((u16)(sv.z >> 16));
    acc[6] = h2f((u16)(sv.w & 0xffff)); acc[7] = h2f((u16)(sv.w >> 16));
  }
  int r0 = rowptr[node], r1 = rowptr[node + 1];
  int idx = r0;
  for (; idx + 1 < r1; idx += 2) {
    int j0 = col[idx], j1 = col[idx + 1];
    uint4 a = *(const uint4*)(hp + (size_t)j0 * DD);
    uint4 b = *(const uint4*)(hp + (size_t)j1 * DD);
    add8(a, acc);
    add8(b, acc);
  }
  if (idx < r1) {
    int j = col[idx];
    uint4 a = *(const uint4*)(hp + (size_t)j * DD);
    add8(a, acc);
  }
  float n = (float)(r1 - r0 + 1);
  uint4 o;
  o.x = pk(sc[0] * acc[0] + n * sh[0], sc[1] * acc[1] + n * sh[1]);
  o.y = pk(sc[2] * acc[2] + n * sh[2], sc[3] * acc[3] + n * sh[3]);
  o.z = pk(sc[4] * acc[4] + n * sh[4], sc[5] * acc[5] + n * sh[5]);
  o.w = pk(sc[6] * acc[6] + n * sh[6], sc[7] * acc[7] + n * sh[7]);
  *(uint4*)(out + (size_t)node * DD + c8) = o;
}

// ---- MFMA GEMM: C[M,512] = relu(A[M,512](fp16) @ W[512,512](fp16,[n][k]) + bias), fp16 out ----
// BM=64 BN=128 BK=64; 256 thr = 4 waves; register-prefetch pipeline.
// STATS=1: per-column sum/sumsq of post-relu C, block-reduced in LDS, then 256 atomics
// into bucket (blockIdx.y & (NBUCK-1)) of stats: [buck*1024 + n | buck*1024 + 512 + n].
template <int STATS>
__global__ __launch_bounds__(256, 4) void mfma_gemm(
    const u16* __restrict__ A, const u16* __restrict__ Wt,
    const float* __restrict__ bias, u16* __restrict__ C, int M,
    float* __restrict__ stats) {
  __shared__ u16 lds[13824];           // 27648 B
  u16* As = lds;                       // [64][72]
  u16* Wh = lds + 4608;                // [128][72]
  const int T = threadIdx.x;
  const int bm = blockIdx.y * 64;
  const int bn = blockIdx.x * 128;
  const int lane = T & 63;
  const int wave = T >> 6;
  const int wm = (wave & 1) * 32;
  const int wn = (wave >> 1) * 64;
  const int q = lane >> 4;
  const int r16 = lane & 15;

  const int arow0 = bm + (T >> 3);
  const int akc = (T & 7) * 8;
  f32x4 acc[2][4] = {};

  uint4 ra[2], rw[4];
#pragma unroll
  for (int p = 0; p < 2; ++p) {
    int grow = arow0 + p * 32;
    ra[p] = make_uint4(0u, 0u, 0u, 0u);
    if (grow < M) ra[p] = *(const uint4*)(A + (size_t)grow * DD + akc);
  }
#pragma unroll
  for (int p = 0; p < 4; ++p) {
    int row = (T + 256 * p) >> 3;
    rw[p] = *(const uint4*)(Wt + (size_t)(bn + row) * DD + akc);
  }

  for (int k0 = 0; k0 < 512; k0 += 64) {
#pragma unroll
    for (int p = 0; p < 2; ++p) {
      int row = (T >> 3) + p * 32;
      *(uint4*)(As + row * 72 + akc) = ra[p];
    }
#pragma unroll
    for (int p = 0; p < 4; ++p) {
      int row = (T + 256 * p) >> 3;
      *(uint4*)(Wh + row * 72 + akc) = rw[p];
    }
    __syncthreads();
    if (k0 + 64 < 512) {
      int kn = k0 + 64;
#pragma unroll
      for (int p = 0; p < 2; ++p) {
        int grow = arow0 + p * 32;
        ra[p] = make_uint4(0u, 0u, 0u, 0u);
        if (grow < M) ra[p] = *(const uint4*)(A + (size_t)grow * DD + kn + akc);
      }
#pragma unroll
      for (int p = 0; p < 4; ++p) {
        int row = (T + 256 * p) >> 3;
        rw[p] = *(const uint4*)(Wt + (size_t)(bn + row) * DD + kn + akc);
      }
    }
#pragma unroll
    for (int ks = 0; ks < 2; ++ks) {
      int kb = ks * 32 + q * 8;
      f16x8 af[2], bh[4];
#pragma unroll
      for (int mt = 0; mt < 2; ++mt)
        af[mt] = *(const f16x8*)(As + (wm + mt * 16 + r16) * 72 + kb);
#pragma unroll
      for (int nt = 0; nt < 4; ++nt)
        bh[nt] = *(const f16x8*)(Wh + (wn + nt * 16 + r16) * 72 + kb);
#pragma unroll
      for (int mt = 0; mt < 2; ++mt)
#pragma unroll
        for (int nt = 0; nt < 4; ++nt)
          acc[mt][nt] = __builtin_amdgcn_mfma_f32_16x16x32_f16(af[mt], bh[nt], acc[mt][nt], 0, 0, 0);
    }
    __syncthreads();
  }

  // epilogue: bias + relu + fp16 store (+ optional block-reduced BN stats)
  float colS[4] = {}, colQ[4] = {};
#pragma unroll
  for (int nt = 0; nt < 4; ++nt) {
    int n = bn + wn + nt * 16 + r16;
    float bv = bias[n];
#pragma unroll
    for (int mt = 0; mt < 2; ++mt) {
#pragma unroll
      for (int rr = 0; rr < 4; ++rr) {
        int row = bm + wm + mt * 16 + q * 4 + rr;
        if (row < M) {
          float v = fmaxf(acc[mt][nt][rr] + bv, 0.f);
          C[(size_t)row * DD + n] = f2h(v);
          if (STATS) { colS[nt] += v; colQ[nt] += v * v; }
        }
      }
    }
  }
  if (STATS) {
    // reduce q-quads within wave -> q==0 lanes hold per-(nt,r16) partials
#pragma unroll
    for (int nt = 0; nt < 4; ++nt) {
      colS[nt] += __shfl_xor(colS[nt], 16); colS[nt] += __shfl_xor(colS[nt], 32);
      colQ[nt] += __shfl_xor(colQ[nt], 16); colQ[nt] += __shfl_xor(colQ[nt], 32);
    }
    float* lsum = (float*)lds;          // [4][64]
    float* lsq = lsum + 256;            // [4][64]
    if (q == 0) {
#pragma unroll
      for (int nt = 0; nt < 4; ++nt) {
        lsum[wave * 64 + nt * 16 + r16] = colS[nt];
        lsq[wave * 64 + nt * 16 + r16] = colQ[nt];
      }
    }
    __syncthreads();
    if (T < 128) {
      int c = T;                         // channel within bn tile
      int wb = (c >> 6) << 1;            // waves {0,1} for c<64, {2,3} for c>=64
      int cc = c & 63;
      float s = lsum[wb * 64 + cc] + lsum[(wb + 1) * 64 + cc];
      float qv = lsq[wb * 64 + cc] + lsq[(wb + 1) * 64 + cc];
      float* sb = stats + (size_t)(blockIdx.y & (NBUCK - 1)) * 1024;
      atomicAdd(&sb[bn + c], s);
      atomicAdd(&sb[512 + bn + c], qv);
    }
  }
}

// ---- pooling: graph boundaries via binary search (batch is sorted) ----
__global__ void k_bounds(const int* __restrict__ batch, int* __restrict__ gstart) {
  int g = threadIdx.x;  // block 128
  if (g > GRAPHS) return;
  if (g == GRAPHS) { gstart[GRAPHS] = NODES; return; }
  int lo = 0, hi = NODES;
  while (lo < hi) {
    int mid = (lo + hi) >> 1;
    if (batch[mid] < g) lo = mid + 1; else hi = mid;
  }
  gstart[g] = lo;
}

// ---- pooled partial sums: grid (GRAPHS, 8 slices), atomics into gsum ----
__global__ __launch_bounds__(128) void k_pool_part(const u16* __restrict__ h, const int* __restrict__ gstart,
                                                   float* __restrict__ gsum) {
  int g = blockIdx.x;
  int s = blockIdx.y;
  int c4 = threadIdx.x * 4;
  int r0 = gstart[g], r1 = gstart[g + 1];
  int cnt = r1 - r0;
  int len = (cnt + 7) >> 3;
  int rs = r0 + s * len;
  int re = min(rs + len, r1);
  if (rs >= re) return;
  float4 acc = make_float4(0.f, 0.f, 0.f, 0.f);
  for (int r = rs; r < re; ++r) {
    ushort4 v = *(const ushort4*)(h + (size_t)r * DD + c4);
    acc.x += h2f(v.x); acc.y += h2f(v.y); acc.z += h2f(v.z); acc.w += h2f(v.w);
  }
  atomicAdd(&gsum[g * DD + c4 + 0], acc.x);
  atomicAdd(&gsum[g * DD + c4 + 1], acc.y);
  atomicAdd(&gsum[g * DD + c4 + 2], acc.z);
  atomicAdd(&gsum[g * DD + c4 + 3], acc.w);
}

// ---- head: feats = tanh(bn(pooled_mean) @ Wfc + bfc); layer-5 BN folded (bucketed stats) ----
__global__ __launch_bounds__(512) void k_head(const float* __restrict__ gsum, const int* __restrict__ gstart,
                                              const float* __restrict__ stats,
                                              const float* __restrict__ gamma, const float* __restrict__ beta,
                                              const float* __restrict__ Wfc, const float* __restrict__ bfc,
                                              float* __restrict__ feats) {
  __shared__ float pv[512];
  int g = blockIdx.x, c = threadIdx.x;
  float inv = 1.f / fmaxf((float)(gstart[g + 1] - gstart[g]), 1.f);
  float s = 0.f, qv = 0.f;
#pragma unroll
  for (int b = 0; b < NBUCK; ++b) {
    s += stats[b * 1024 + c];
    qv += stats[b * 1024 + 512 + c];
  }
  float mean = s * (1.f / NODES);
  float var = qv * (1.f / NODES) - mean * mean;
  float sc = gamma[c] * rsqrtf(var + BN_EPS);
  float sh = beta[c] - mean * sc;
  pv[c] = gsum[g * DD + c] * inv * sc + sh;
  __syncthreads();
  float acc = bfc[c];
  for (int k = 0; k < DD; ++k)
    acc = fmaf(pv[k], Wfc[k * DD + c], acc);
  feats[g * DD + c] = tanhf(acc);
}

// ---- logits = feats @ Wlog + blog, out fp32 ----
__global__ void k_logits(const float* __restrict__ feats, const float* __restrict__ Wlog,
                         const float* __restrict__ blog, float* __restrict__ out) {
  int g = blockIdx.x, o = threadIdx.x;
  if (o >= NOUT) return;
  float acc = blog[o];
  const float* f = feats + g * DD;
  for (int k = 0; k < DD; ++k)
    acc = fmaf(f[k], Wlog[k * NOUT + o], acc);
  out[g * NOUT + o] = acc;
}

extern "C" void kernel_launch(void* const* d_in, const int* in_sizes, int n_in,
                              void* d_out, int out_size, void* d_ws, size_t ws_size,
                              hipStream_t stream) {
  const float* x = (const float*)d_in[0];
  const int* ei = (const int*)d_in[1];
  const int* batch = (const int*)d_in[2];
  const float* W1a = (const float*)d_in[3];
  const float* b1a = (const float*)d_in[4];
  const float* W1b = (const float*)d_in[5];
  const float* b1b = (const float*)d_in[6];
  const float* Wa = (const float*)d_in[7];
  const float* ba = (const float*)d_in[8];
  const float* Wb = (const float*)d_in[9];
  const float* bb = (const float*)d_in[10];
  const float* bng = (const float*)d_in[11];
  const float* bnb = (const float*)d_in[12];
  const float* Wfc = (const float*)d_in[13];
  const float* bfc = (const float*)d_in[14];
  const float* Wlog = (const float*)d_in[15];
  const float* blog = (const float*)d_in[16];
  float* out = (float*)d_out;

  const int* src = ei;
  const int* dstp = ei + EDGES;

  char* w = (char*)d_ws;
  int* rowptr  = (int*)(w);                 // 10001 i32
  int* cur     = (int*)(w + 40192);         // 10000 i32
  int* col     = (int*)(w + 80384);         // 160000 i32
  float* h0    = (float*)(w + 720384);      // 160000 f
  float* bns   = (float*)(w + 1360384);     // 5 layers x NBUCK x 1024 f = 40960 f
  float* gsum  = (float*)(w + 1524224);     // 32768 f (contiguous after bns for joint zeroing)
  int* gstart  = (int*)(w + 1655296);       // 65 i32 (pad 512 B)
  float* feats = (float*)(w + 1655808);     // 32768 f
  u16* Wt      = (u16*)(w + 1786880);       // 9 x 262144 u16 = 4.72 MB
  u16* P0      = (u16*)(w + 6505472);       // 5,120,000 fp16
  u16* P1      = (u16*)(w + 16745472);      // 5,120,000 fp16 (end ~27.0 MB)

  // CSR build
  k_zero_i32<<<40, 256, 0, stream>>>(cur, NODES);
  k_count<<<625, 256, 0, stream>>>(dstp, cur);
  k_scan<<<1, 1024, 0, stream>>>(cur, rowptr);
  k_zero_i32<<<40, 256, 0, stream>>>(cur, NODES);
  k_fill<<<625, 256, 0, stream>>>(src, dstp, rowptr, cur, col);

  // zero bns (40960) + gsum (32768) in one pass: 73728 floats
  k_zero_f32<<<288, 256, 0, stream>>>(bns, 73728);

  // weight transpose to fp16 (9 DxD matrices)
  k_wsplit<<<dim3(16, 16, 9), 256, 0, stream>>>(W1b, Wa, Wb, Wt);

  // layer 1
  k_agg16<<<625, 256, 0, stream>>>(x, rowptr, col, h0);
  k_gemm_k16<<<dim3(2, NODES), 256, 0, stream>>>(h0, W1a, b1a, P0);
  mfma_gemm<1><<<dim3(4, 157), 256, 0, stream>>>(P0, Wt, b1b, P1, NODES, bns);

  // layers 2..5: H -> agg+bn(bucket fold) -> T -> mfma(Wa) -> H -> mfma(Wb)+stats -> T
  u16* H = P1;
  u16* T = P0;
  for (int i = 0; i < 4; ++i) {
    k_agg512_bn<<<2500, 256, 0, stream>>>(H, rowptr, col, bns + (size_t)i * NBUCK * 1024,
                                          bng + i * DD, bnb + i * DD, T);
    mfma_gemm<0><<<dim3(4, 157), 256, 0, stream>>>(T, Wt + (size_t)(1 + i) * 262144, ba + i * DD, H, NODES, nullptr);
    mfma_gemm<1><<<dim3(4, 157), 256, 0, stream>>>(H, Wt + (size_t)(5 + i) * 262144, bb + i * DD, T, NODES,
                                                   bns + (size_t)(i + 1) * NBUCK * 1024);
    u16* tmp = H; H = T; T = tmp;
  }

  // pooling (parallel partials) + head (layer-5 BN folded) + logits
  k_bounds<<<1, 128, 0, stream>>>(batch, gstart);
  k_pool_part<<<dim3(GRAPHS, 8), 128, 0, stream>>>(H, gstart, gsum);
  k_head<<<GRAPHS, 512, 0, stream>>>(gsum, gstart, bns + (size_t)4 * NBUCK * 1024,
                                     bng + 4 * DD, bnb + 4 * DD, Wfc, bfc, feats);
  k_logits<<<GRAPHS, 64, 0, stream>>>(feats, Wlog, blog, out);
}

// Round 10
// 603.151 us; speedup vs baseline: 2.3443x; 1.0507x over previous
//
#include <hip/hip_runtime.h>

#define NODES 10000
#define EDGES 160000
#define INF_ 16
#define DD 512
#define GRAPHS 64
#define NOUT 18
#define BN_EPS 1e-5f
#define NBUCK 8

using u16 = unsigned short;
typedef __attribute__((ext_vector_type(8))) _Float16 f16x8;
typedef __attribute__((ext_vector_type(4))) float f32x4;

__device__ __forceinline__ float h2f(u16 u) {
  union { u16 u; _Float16 h; } v; v.u = u; return (float)v.h;
}
__device__ __forceinline__ u16 f2h(float f) {
  union { u16 u; _Float16 h; } v; v.h = (_Float16)f; return v.u;
}
__device__ __forceinline__ void add8(uint4 u, float* a) {
  a[0] += h2f((u16)(u.x & 0xffff)); a[1] += h2f((u16)(u.x >> 16));
  a[2] += h2f((u16)(u.y & 0xffff)); a[3] += h2f((u16)(u.y >> 16));
  a[4] += h2f((u16)(u.z & 0xffff)); a[5] += h2f((u16)(u.z >> 16));
  a[6] += h2f((u16)(u.w & 0xffff)); a[7] += h2f((u16)(u.w >> 16));
}
__device__ __forceinline__ unsigned int pk(float a, float b) {
  return (unsigned int)f2h(a) | ((unsigned int)f2h(b) << 16);
}
__device__ __forceinline__ int lower_bound_dev(const int* __restrict__ batch, int g) {
  int lo = 0, hi = NODES;
  while (lo < hi) { int m = (lo + hi) >> 1; if (batch[m] < g) lo = m + 1; else hi = m; }
  return lo;
}

// ---- setup: zero cur (10000 i32) + bns|gsum (73728 f) ----
__global__ void k_setup(int* __restrict__ cur, float* __restrict__ bg) {
  int i = blockIdx.x * 256 + threadIdx.x;
  if (i < NODES) cur[i] = 0;
  if (i < 73728) bg[i] = 0.f;
}

// ---- CSR build (dst-indexed): count -> scan(+reset) -> fill ----
__global__ void k_count(const int* __restrict__ dst, int* __restrict__ cnt) {
  int e = blockIdx.x * 256 + threadIdx.x;
  if (e < EDGES) atomicAdd(&cnt[dst[e]], 1);
}

__global__ __launch_bounds__(1024) void k_scan(int* __restrict__ cnt, int* __restrict__ rowptr) {
  __shared__ int s[1024];
  int t = threadIdx.x;
  int base = t * 10;
  int c[10]; int sum = 0;
#pragma unroll
  for (int i = 0; i < 10; ++i) {
    int idx = base + i;
    c[i] = (idx < NODES) ? cnt[idx] : 0;
    if (idx < NODES) cnt[idx] = 0;   // reset for k_fill's running cursor
    sum += c[i];
  }
  s[t] = sum; __syncthreads();
  for (int off = 1; off < 1024; off <<= 1) {
    int v = s[t];
    int a = (t >= off) ? s[t - off] : 0;
    __syncthreads();
    s[t] = v + a;
    __syncthreads();
  }
  int run = (t == 0) ? 0 : s[t - 1];
#pragma unroll
  for (int i = 0; i < 10; ++i) { int idx = base + i; if (idx < NODES) rowptr[idx] = run; run += c[i]; }
  if (t == 1023) rowptr[NODES] = s[1023];
}

__global__ void k_fill(const int* __restrict__ src, const int* __restrict__ dst,
                       const int* __restrict__ rowptr, int* __restrict__ cur, int* __restrict__ col) {
  int e = blockIdx.x * 256 + threadIdx.x;
  if (e < EDGES) {
    int d = dst[e];
    int p = atomicAdd(&cur[d], 1);
    col[rowptr[d] + p] = src[e];
  }
}

// ---- W transpose to fp16 [n][k]: Wt[n][k] = W[k][n] ----
__global__ __launch_bounds__(256) void k_wsplit(const float* __restrict__ W1b, const float* __restrict__ Wa,
                                                const float* __restrict__ Wb, u16* __restrict__ Wt) {
  __shared__ float tile[32][33];
  int z = blockIdx.z;
  const float* src = (z == 0) ? W1b : (z <= 4 ? Wa + (z - 1) * DD * DD : Wb + (z - 5) * DD * DD);
  int kb = blockIdx.y * 32, nb = blockIdx.x * 32;
  int tx = threadIdx.x & 31, ty = threadIdx.x >> 5;  // 32 x 8
#pragma unroll
  for (int i = 0; i < 4; ++i)
    tile[ty + 8 * i][tx] = src[(kb + ty + 8 * i) * DD + nb + tx];
  __syncthreads();
  u16* hi = Wt + (size_t)z * 262144;
#pragma unroll
  for (int i = 0; i < 4; ++i) {
    int n = nb + ty + 8 * i, k = kb + tx;
    hi[n * DD + k] = f2h(tile[tx][ty + 8 * i]);
  }
}

// ---- layer 1 fused: agg16 (LDS) + relu(h0 @ W1a + b1a), fp16 out ----
// block = 16 nodes; phase 1: 256 thr = 16 nodes x 16 ch gather; phase 2: K=16 gemm.
__global__ __launch_bounds__(256) void k_l1(const float* __restrict__ x, const int* __restrict__ rowptr,
                                            const int* __restrict__ col, const float* __restrict__ W1a,
                                            const float* __restrict__ b1a, u16* __restrict__ out) {
  __shared__ float sh0[16][17];
  int t = threadIdx.x;
  int nl = t >> 4, ch = t & 15;
  int node = blockIdx.x * 16 + nl;   // 625*16 = 10000 exact
  float acc = x[node * INF_ + ch];
  int r1 = rowptr[node + 1];
  for (int idx = rowptr[node]; idx < r1; ++idx)
    acc += x[col[idx] * INF_ + ch];
  sh0[nl][ch] = acc;
  __syncthreads();
#pragma unroll
  for (int p = 0; p < 2; ++p) {
    int c = t + 256 * p;
    float wreg[16];
#pragma unroll
    for (int k = 0; k < 16; ++k) wreg[k] = W1a[k * DD + c];
    float bv = b1a[c];
#pragma unroll
    for (int r = 0; r < 16; ++r) {
      float s = bv;
#pragma unroll
      for (int k = 0; k < 16; ++k) s = fmaf(sh0[r][k], wreg[k], s);
      out[(size_t)(blockIdx.x * 16 + r) * DD + c] = f2h(fmaxf(s, 0.f));
    }
  }
}

// ---- fused aggregation + BN(finalize from bucketed stats) + apply, [NODES,512] fp16 ----
// wave-per-node, 4 nodes/block, 4-way neighbor unroll for MLP.
__global__ __launch_bounds__(256) void k_agg512_bn(const u16* __restrict__ h, const int* __restrict__ rowptr,
                                                   const int* __restrict__ col, const float* __restrict__ stats,
                                                   const float* __restrict__ gamma, const float* __restrict__ beta,
                                                   u16* __restrict__ out) {
  __shared__ float ssc[512], ssh[512];
  int t = threadIdx.x;
#pragma unroll
  for (int r = 0; r < 2; ++r) {
    int c = t + r * 256;
    float s = 0.f, qv = 0.f;
#pragma unroll
    for (int b = 0; b < NBUCK; ++b) {
      s += stats[b * 1024 + c];
      qv += stats[b * 1024 + 512 + c];
    }
    float mean = s * (1.f / NODES);
    float var = qv * (1.f / NODES) - mean * mean;
    float sc = gamma[c] * rsqrtf(var + BN_EPS);
    ssc[c] = sc;
    ssh[c] = beta[c] - mean * sc;
  }
  __syncthreads();

  int lane = t & 63;
  int node = blockIdx.x * 4 + (t >> 6);   // grid 2500 x 4 = 10000 exact
  int c8 = lane * 8;
  float sc[8], sh[8];
#pragma unroll
  for (int k = 0; k < 8; ++k) { sc[k] = ssc[c8 + k]; sh[k] = ssh[c8 + k]; }

  const u16* hp = h + c8;
  float acc[8];
  {
    uint4 sv = *(const uint4*)(hp + (size_t)node * DD);
    acc[0] = h2f((u16)(sv.x & 0xffff)); acc[1] = h2f((u16)(sv.x >> 16));
    acc[2] = h2f((u16)(sv.y & 0xffff)); acc[3] = h2f((u16)(sv.y >> 16));
    acc[4] = h2f((u16)(sv.z & 0xffff)); acc[5] = h2f((u16)(sv.z >> 16));
    acc[6] = h2f((u16)(sv.w & 0xffff)); acc[7] = h2f((u16)(sv.w >> 16));
  }
  int r0 = rowptr[node], r1 = rowptr[node + 1];
  int idx = r0;
  for (; idx + 3 < r1; idx += 4) {
    int j0 = col[idx], j1 = col[idx + 1], j2 = col[idx + 2], j3 = col[idx + 3];
    uint4 a = *(const uint4*)(hp + (size_t)j0 * DD);
    uint4 b = *(const uint4*)(hp + (size_t)j1 * DD);
    uint4 c = *(const uint4*)(hp + (size_t)j2 * DD);
    uint4 d = *(const uint4*)(hp + (size_t)j3 * DD);
    add8(a, acc); add8(b, acc); add8(c, acc); add8(d, acc);
  }
  for (; idx < r1; ++idx) {
    int j = col[idx];
    uint4 a = *(const uint4*)(hp + (size_t)j * DD);
    add8(a, acc);
  }
  float n = (float)(r1 - r0 + 1);
  uint4 o;
  o.x = pk(sc[0] * acc[0] + n * sh[0], sc[1] * acc[1] + n * sh[1]);
  o.y = pk(sc[2] * acc[2] + n * sh[2], sc[3] * acc[3] + n * sh[3]);
  o.z = pk(sc[4] * acc[4] + n * sh[4], sc[5] * acc[5] + n * sh[5]);
  o.w = pk(sc[6] * acc[6] + n * sh[6], sc[7] * acc[7] + n * sh[7]);
  *(uint4*)(out + (size_t)node * DD + c8) = o;
}

// ---- MFMA GEMM: C[M,512] = relu(A[M,512](fp16) @ W[512,512](fp16,[n][k]) + bias), fp16 out ----
// 1-D grid 628, XCD-swizzled so the 4 bn-blocks of one bm-slab share an XCD (A fetched once).
// BM=64 BN=128 BK=64; register-prefetch pipeline. STATS=1: bucketed block-reduced BN stats.
template <int STATS>
__global__ __launch_bounds__(256, 4) void mfma_gemm(
    const u16* __restrict__ A, const u16* __restrict__ Wt,
    const float* __restrict__ bias, u16* __restrict__ C, int M,
    float* __restrict__ stats) {
  __shared__ u16 lds[13824];           // 27648 B
  u16* As = lds;                       // [64][72]
  u16* Wh = lds + 4608;                // [128][72]
  const int T = threadIdx.x;
  int id = blockIdx.x;
  int bm_i, bn_i;
  if (id < 608) { int gi = id >> 5, r = id & 31; bm_i = gi * 8 + (r & 7); bn_i = r >> 3; }
  else { int r = id - 608; bm_i = 152 + (r % 5); bn_i = r / 5; }
  const int bm = bm_i * 64;
  const int bn = bn_i * 128;
  const int lane = T & 63;
  const int wave = T >> 6;
  const int wm = (wave & 1) * 32;
  const int wn = (wave >> 1) * 64;
  const int q = lane >> 4;
  const int r16 = lane & 15;

  const int arow0 = bm + (T >> 3);
  const int akc = (T & 7) * 8;
  f32x4 acc[2][4] = {};

  uint4 ra[2], rw[4];
#pragma unroll
  for (int p = 0; p < 2; ++p) {
    int grow = arow0 + p * 32;
    ra[p] = make_uint4(0u, 0u, 0u, 0u);
    if (grow < M) ra[p] = *(const uint4*)(A + (size_t)grow * DD + akc);
  }
#pragma unroll
  for (int p = 0; p < 4; ++p) {
    int row = (T + 256 * p) >> 3;
    rw[p] = *(const uint4*)(Wt + (size_t)(bn + row) * DD + akc);
  }

  for (int k0 = 0; k0 < 512; k0 += 64) {
#pragma unroll
    for (int p = 0; p < 2; ++p) {
      int row = (T >> 3) + p * 32;
      *(uint4*)(As + row * 72 + akc) = ra[p];
    }
#pragma unroll
    for (int p = 0; p < 4; ++p) {
      int row = (T + 256 * p) >> 3;
      *(uint4*)(Wh + row * 72 + akc) = rw[p];
    }
    __syncthreads();
    if (k0 + 64 < 512) {
      int kn = k0 + 64;
#pragma unroll
      for (int p = 0; p < 2; ++p) {
        int grow = arow0 + p * 32;
        ra[p] = make_uint4(0u, 0u, 0u, 0u);
        if (grow < M) ra[p] = *(const uint4*)(A + (size_t)grow * DD + kn + akc);
      }
#pragma unroll
      for (int p = 0; p < 4; ++p) {
        int row = (T + 256 * p) >> 3;
        rw[p] = *(const uint4*)(Wt + (size_t)(bn + row) * DD + kn + akc);
      }
    }
#pragma unroll
    for (int ks = 0; ks < 2; ++ks) {
      int kb = ks * 32 + q * 8;
      f16x8 af[2], bh[4];
#pragma unroll
      for (int mt = 0; mt < 2; ++mt)
        af[mt] = *(const f16x8*)(As + (wm + mt * 16 + r16) * 72 + kb);
#pragma unroll
      for (int nt = 0; nt < 4; ++nt)
        bh[nt] = *(const f16x8*)(Wh + (wn + nt * 16 + r16) * 72 + kb);
#pragma unroll
      for (int mt = 0; mt < 2; ++mt)
#pragma unroll
        for (int nt = 0; nt < 4; ++nt)
          acc[mt][nt] = __builtin_amdgcn_mfma_f32_16x16x32_f16(af[mt], bh[nt], acc[mt][nt], 0, 0, 0);
    }
    __syncthreads();
  }

  float colS[4] = {}, colQ[4] = {};
#pragma unroll
  for (int nt = 0; nt < 4; ++nt) {
    int n = bn + wn + nt * 16 + r16;
    float bv = bias[n];
#pragma unroll
    for (int mt = 0; mt < 2; ++mt) {
#pragma unroll
      for (int rr = 0; rr < 4; ++rr) {
        int row = bm + wm + mt * 16 + q * 4 + rr;
        if (row < M) {
          float v = fmaxf(acc[mt][nt][rr] + bv, 0.f);
          C[(size_t)row * DD + n] = f2h(v);
          if (STATS) { colS[nt] += v; colQ[nt] += v * v; }
        }
      }
    }
  }
  if (STATS) {
#pragma unroll
    for (int nt = 0; nt < 4; ++nt) {
      colS[nt] += __shfl_xor(colS[nt], 16); colS[nt] += __shfl_xor(colS[nt], 32);
      colQ[nt] += __shfl_xor(colQ[nt], 16); colQ[nt] += __shfl_xor(colQ[nt], 32);
    }
    float* lsum = (float*)lds;          // [4][64]
    float* lsq = lsum + 256;            // [4][64]
    if (q == 0) {
#pragma unroll
      for (int nt = 0; nt < 4; ++nt) {
        lsum[wave * 64 + nt * 16 + r16] = colS[nt];
        lsq[wave * 64 + nt * 16 + r16] = colQ[nt];
      }
    }
    __syncthreads();
    if (T < 128) {
      int c = T;
      int wb = (c >> 6) << 1;
      int cc = c & 63;
      float s = lsum[wb * 64 + cc] + lsum[(wb + 1) * 64 + cc];
      float qv = lsq[wb * 64 + cc] + lsq[(wb + 1) * 64 + cc];
      float* sb = stats + (size_t)(bm_i & (NBUCK - 1)) * 1024;
      atomicAdd(&sb[bn + c], s);
      atomicAdd(&sb[512 + bn + c], qv);
    }
  }
}

// ---- pooled partial sums: grid (GRAPHS, 8 slices), per-block binary-search bounds ----
__global__ __launch_bounds__(128) void k_pool_part(const u16* __restrict__ h, const int* __restrict__ batch,
                                                   float* __restrict__ gsum) {
  int g = blockIdx.x;
  int s = blockIdx.y;
  int c4 = threadIdx.x * 4;
  int r0 = lower_bound_dev(batch, g);
  int r1 = lower_bound_dev(batch, g + 1);
  int cnt = r1 - r0;
  int len = (cnt + 7) >> 3;
  int rs = r0 + s * len;
  int re = min(rs + len, r1);
  if (rs >= re) return;
  float4 acc = make_float4(0.f, 0.f, 0.f, 0.f);
  for (int r = rs; r < re; ++r) {
    ushort4 v = *(const ushort4*)(h + (size_t)r * DD + c4);
    acc.x += h2f(v.x); acc.y += h2f(v.y); acc.z += h2f(v.z); acc.w += h2f(v.w);
  }
  atomicAdd(&gsum[g * DD + c4 + 0], acc.x);
  atomicAdd(&gsum[g * DD + c4 + 1], acc.y);
  atomicAdd(&gsum[g * DD + c4 + 2], acc.z);
  atomicAdd(&gsum[g * DD + c4 + 3], acc.w);
}

// ---- head+logits fused: feats = tanh(bn(mean) @ Wfc + bfc); out = feats @ Wlog + blog ----
__global__ __launch_bounds__(512) void k_headlog(const float* __restrict__ gsum, const int* __restrict__ batch,
                                                 const float* __restrict__ stats,
                                                 const float* __restrict__ gamma, const float* __restrict__ beta,
                                                 const float* __restrict__ Wfc, const float* __restrict__ bfc,
                                                 const float* __restrict__ Wlog, const float* __restrict__ blog,
                                                 float* __restrict__ out) {
  __shared__ float pv[512];
  __shared__ float fv[512];
  int g = blockIdx.x, c = threadIdx.x;
  int r0 = lower_bound_dev(batch, g);
  int r1 = lower_bound_dev(batch, g + 1);
  float inv = 1.f / fmaxf((float)(r1 - r0), 1.f);
  float s = 0.f, qv = 0.f;
#pragma unroll
  for (int b = 0; b < NBUCK; ++b) {
    s += stats[b * 1024 + c];
    qv += stats[b * 1024 + 512 + c];
  }
  float mean = s * (1.f / NODES);
  float var = qv * (1.f / NODES) - mean * mean;
  float sc = gamma[c] * rsqrtf(var + BN_EPS);
  float sh = beta[c] - mean * sc;
  pv[c] = gsum[g * DD + c] * inv * sc + sh;
  __syncthreads();
  float acc = bfc[c];
  for (int k = 0; k < DD; ++k)
    acc = fmaf(pv[k], Wfc[k * DD + c], acc);
  fv[c] = tanhf(acc);
  __syncthreads();
  if (c < NOUT) {
    float lg = blog[c];
    for (int k = 0; k < DD; ++k)
      lg = fmaf(fv[k], Wlog[k * NOUT + c], lg);
    out[g * NOUT + c] = lg;
  }
}

extern "C" void kernel_launch(void* const* d_in, const int* in_sizes, int n_in,
                              void* d_out, int out_size, void* d_ws, size_t ws_size,
                              hipStream_t stream) {
  const float* x = (const float*)d_in[0];
  const int* ei = (const int*)d_in[1];
  const int* batch = (const int*)d_in[2];
  const float* W1a = (const float*)d_in[3];
  const float* b1a = (const float*)d_in[4];
  const float* W1b = (const float*)d_in[5];
  const float* b1b = (const float*)d_in[6];
  const float* Wa = (const float*)d_in[7];
  const float* ba = (const float*)d_in[8];
  const float* Wb = (const float*)d_in[9];
  const float* bb = (const float*)d_in[10];
  const float* bng = (const float*)d_in[11];
  const float* bnb = (const float*)d_in[12];
  const float* Wfc = (const float*)d_in[13];
  const float* bfc = (const float*)d_in[14];
  const float* Wlog = (const float*)d_in[15];
  const float* blog = (const float*)d_in[16];
  float* out = (float*)d_out;

  const int* src = ei;
  const int* dstp = ei + EDGES;

  char* w = (char*)d_ws;
  int* rowptr = (int*)(w);                  // 10001 i32 (pad 40192)
  int* cur    = (int*)(w + 40192);          // 10000 i32
  int* col    = (int*)(w + 80384);          // 160000 i32 -> ends 720384
  float* bns  = (float*)(w + 720384);       // 5 x NBUCK x 1024 f = 40960 f
  float* gsum = (float*)(w + 884224);       // 32768 f (contiguous after bns) -> ends 1015296
  u16* Wt     = (u16*)(w + 1015296);        // 9 x 262144 u16 = 4.72 MB -> ends 5733888
  u16* P0     = (u16*)(w + 5733888);        // 5,120,000 fp16
  u16* P1     = (u16*)(w + 15973888);       // 5,120,000 fp16 (end ~26.2 MB)

  // setup (zero cur + bns + gsum) and CSR build
  k_setup<<<288, 256, 0, stream>>>(cur, bns);
  k_count<<<625, 256, 0, stream>>>(dstp, cur);
  k_scan<<<1, 1024, 0, stream>>>(cur, rowptr);   // also resets cur to 0
  k_fill<<<625, 256, 0, stream>>>(src, dstp, rowptr, cur, col);

  // weight transpose to fp16 (9 DxD matrices)
  k_wsplit<<<dim3(16, 16, 9), 256, 0, stream>>>(W1b, Wa, Wb, Wt);

  // layer 1: fused agg16 + K16 gemm -> P0, then big gemm + stats
  k_l1<<<625, 256, 0, stream>>>(x, rowptr, col, W1a, b1a, P0);
  mfma_gemm<1><<<628, 256, 0, stream>>>(P0, Wt, b1b, P1, NODES, bns);

  // layers 2..5: H -> agg+bn -> T -> mfma(Wa) -> H -> mfma(Wb)+stats -> T
  u16* H = P1;
  u16* T = P0;
  for (int i = 0; i < 4; ++i) {
    k_agg512_bn<<<2500, 256, 0, stream>>>(H, rowptr, col, bns + (size_t)i * NBUCK * 1024,
                                          bng + i * DD, bnb + i * DD, T);
    mfma_gemm<0><<<628, 256, 0, stream>>>(T, Wt + (size_t)(1 + i) * 262144, ba + i * DD, H, NODES, nullptr);
    mfma_gemm<1><<<628, 256, 0, stream>>>(H, Wt + (size_t)(5 + i) * 262144, bb + i * DD, T, NODES,
                                          bns + (size_t)(i + 1) * NBUCK * 1024);
    u16* tmp = H; H = T; T = tmp;
  }

  // pooling + fused head/logits (layer-5 BN folded)
  k_pool_part<<<dim3(GRAPHS, 8), 128, 0, stream>>>(H, batch, gsum);
  k_headlog<<<GRAPHS, 512, 0, stream>>>(gsum, batch, bns + (size_t)4 * NBUCK * 1024,
                                        bng + 4 * DD, bnb + 4 * DD, Wfc, bfc, Wlog, blog, out);
}